// Round 5
// baseline (428.265 us; speedup 1.0000x reference)
//
#include <hip/hip_runtime.h>
#include <hip/hip_bf16.h>
#include <math.h>

#define NMAT  50000
#define NOPS  100000
#define NEDGE 512000
#define DOPR  192
#define DEAT  64

typedef __attribute__((ext_vector_type(8))) short bfx8;
typedef __attribute__((ext_vector_type(4))) float fx4;

static __device__ __forceinline__ float lrelu(float x) { return x > 0.f ? x : 0.2f * x; }
static __device__ __forceinline__ float elu(float x)   { return x > 0.f ? x : expm1f(x); }
static __device__ __forceinline__ unsigned short f2bf(float x) {
    unsigned int b = __float_as_uint(x);
    return (unsigned short)((b + 0x7fffu + ((b >> 16) & 1u)) >> 16);   // RNE
}
static __device__ __forceinline__ float bflo(unsigned int u) { return __uint_as_float(u << 16); }
static __device__ __forceinline__ float bfhi(unsigned int u) { return __uint_as_float(u & 0xffff0000u); }
static __device__ __forceinline__ float bf1(unsigned short u) { return __uint_as_float(((unsigned int)u) << 16); }

// ---------------- prep (block 0) + weight bf16-transpose conv (blocks 1..96) ----------
__launch_bounds__(256)
__global__ void k_prepconv(const float* __restrict__ att_self, const float* __restrict__ att_cross,
                           const float* __restrict__ W_mat, const float* __restrict__ W_op,
                           float* __restrict__ asum, float* __restrict__ wv,
                           float* __restrict__ wmc0, float* __restrict__ wmas,
                           float* __restrict__ woc1,
                           unsigned short* __restrict__ BtM, unsigned short* __restrict__ BtO)
{
    const int b = blockIdx.x, t = threadIdx.x;
    if (b == 0) {
        __shared__ float as_sh[128];
        if (t < 128) { float v = att_self[t] + att_self[128 + t]; asum[t] = v; as_sh[t] = v; }
        __syncthreads();
        if (t < 128) {
            const float* wr = W_mat + (size_t)t * 128;
            float p0 = 0.f, p1 = 0.f;
            for (int j = 0; j < 128; ++j) { p0 += wr[j] * att_cross[j]; p1 += wr[j] * as_sh[j]; }
            wmc0[t] = p0; wmas[t] = p1;
        }
        const float* wr = W_op + (size_t)t * 128;
        float p = 0.f;
        for (int j = 0; j < 128; ++j) p += wr[j] * att_cross[128 + j];
        if (t < DOPR) woc1[t] = p; else wv[t - DOPR] = p;
    } else {
        int id = (b - 1) * 256 + t;
        if (id < 128 * 128) {
            int c = id >> 7, k = id & 127;
            BtM[c * 128 + k] = f2bf(W_mat[(size_t)k * 128 + c]);
        }
        if (id < 128 * DOPR) {
            int c = id / DOPR, k = id % DOPR;
            BtO[c * DOPR + k] = f2bf(W_op[(size_t)k * 128 + c]);
        }
    }
}

// ---------------- MFMA GEMM: Cb[M][cstride] = bf16(A[M][K] @ B), fused fp32 row-dots ----
// MODE 1: d1 = A.v1 (dm), d2 = lrelu(A.v2) (s_self).  MODE 2: d1 = A.v1 (dop).
template<int K, int MODE>
__launch_bounds__(256)
__global__ void gemm_mfma(const float* __restrict__ A, const unsigned short* __restrict__ Bt,
                          unsigned short* __restrict__ Cb, int cstride,
                          const float* __restrict__ v1, const float* __restrict__ v2,
                          float* __restrict__ d1, float* __restrict__ d2, int M)
{
    __shared__ unsigned short As[128 * 40];   // [row][k], stride 40
    __shared__ unsigned short Bs[128 * 40];   // [col][k]
    const int t = threadIdx.x;
    const int w = t >> 6, l = t & 63;
    const int lr = l & 15, lk = l >> 4;
    const int row0 = blockIdx.x * 128;

    fx4 acc[2][8];
#pragma unroll
    for (int i = 0; i < 2; ++i)
#pragma unroll
        for (int j = 0; j < 8; ++j) acc[i][j] = (fx4){0.f, 0.f, 0.f, 0.f};
    float pd1[4] = {0.f, 0.f, 0.f, 0.f};
    float pd2[4] = {0.f, 0.f, 0.f, 0.f};

    for (int k0 = 0; k0 < K; k0 += 32) {
#pragma unroll
        for (int it = 0; it < 4; ++it) {             // stage A (fp32 -> bf16) + dot partials
            int q  = t + 256 * it;
            int r  = q >> 3;
            int kk = (q & 7) * 4;
            int gr = row0 + r; if (gr >= M) gr = M - 1;
            float4 v = *reinterpret_cast<const float4*>(A + (size_t)gr * K + k0 + kk);
            ushort4 bb = {f2bf(v.x), f2bf(v.y), f2bf(v.z), f2bf(v.w)};
            *reinterpret_cast<ushort4*>(&As[r * 40 + kk]) = bb;
            pd1[it] += v.x * v1[k0 + kk] + v.y * v1[k0 + kk + 1]
                     + v.z * v1[k0 + kk + 2] + v.w * v1[k0 + kk + 3];
            if (MODE == 1)
                pd2[it] += v.x * v2[k0 + kk] + v.y * v2[k0 + kk + 1]
                         + v.z * v2[k0 + kk + 2] + v.w * v2[k0 + kk + 3];
        }
#pragma unroll
        for (int it = 0; it < 2; ++it) {             // stage B chunk (bf16, pre-transposed)
            int q  = t + 256 * it;
            int c  = q >> 2;
            int kg = (q & 3) * 8;
            uint4 vb = *reinterpret_cast<const uint4*>(&Bt[(size_t)c * K + k0 + kg]);
            *reinterpret_cast<uint4*>(&Bs[c * 40 + kg]) = vb;
        }
        __syncthreads();
        bfx8 af0 = *reinterpret_cast<const bfx8*>(&As[(w * 32 + lr) * 40 + lk * 8]);
        bfx8 af1 = *reinterpret_cast<const bfx8*>(&As[(w * 32 + 16 + lr) * 40 + lk * 8]);
#pragma unroll
        for (int ni = 0; ni < 8; ++ni) {
            bfx8 bf = *reinterpret_cast<const bfx8*>(&Bs[(ni * 16 + lr) * 40 + lk * 8]);
            acc[0][ni] = __builtin_amdgcn_mfma_f32_16x16x32_bf16(af0, bf, acc[0][ni], 0, 0, 0);
            acc[1][ni] = __builtin_amdgcn_mfma_f32_16x16x32_bf16(af1, bf, acc[1][ni], 0, 0, 0);
        }
        __syncthreads();
    }

    // C/D layout: col = lane&15, row = (lane>>4)*4 + reg
#pragma unroll
    for (int mi = 0; mi < 2; ++mi)
#pragma unroll
        for (int ni = 0; ni < 8; ++ni)
#pragma unroll
            for (int r2 = 0; r2 < 4; ++r2) {
                int row = row0 + w * 32 + mi * 16 + lk * 4 + r2;
                int col = ni * 16 + lr;
                if (row < M) Cb[(size_t)row * cstride + col] = f2bf(acc[mi][ni][r2]);
            }

    // fused row dots: 8 consecutive threads share one tile row
#pragma unroll
    for (int it = 0; it < 4; ++it) {
        float p1 = pd1[it], p2 = pd2[it];
#pragma unroll
        for (int off = 1; off < 8; off <<= 1) {
            p1 += __shfl_xor(p1, off, 8);
            if (MODE == 1) p2 += __shfl_xor(p2, off, 8);
        }
        int r  = (t + 256 * it) >> 3;
        int gr = row0 + r;
        if ((t & 7) == 0 && gr < M) {
            d1[gr] = p1;
            if (MODE == 1) d2[gr] = lrelu(p2);
        }
    }
}

// ---------------- edge scores + dst histogram ----------------
__launch_bounds__(256)
__global__ void k_edge_score(const float* __restrict__ edge_attr,
                             const int* __restrict__ esrc, const int* __restrict__ edst,
                             const float* __restrict__ dm, const float* __restrict__ dop,
                             const float* __restrict__ wv, float* __restrict__ s,
                             int* __restrict__ cnt)
{
    int t = threadIdx.x;
    int g = t >> 4, q = t & 15;
    float4 wvq = *reinterpret_cast<const float4*>(wv + q * 4);
#pragma unroll
    for (int u = 0; u < 8; ++u) {
        int e = blockIdx.x * 128 + u * 16 + g;
        float4 av = *reinterpret_cast<const float4*>(edge_attr + (size_t)e * DEAT + q * 4);
        float p = av.x * wvq.x + av.y * wvq.y + av.z * wvq.z + av.w * wvq.w;
#pragma unroll
        for (int off = 1; off < 16; off <<= 1) p += __shfl_xor(p, off, 16);
        if (q == 0) {
            int d = edst[e];
            s[NMAT + e] = lrelu(p + dm[d] + dop[esrc[e]]);
            atomicAdd(&cnt[d], 1);
        }
    }
}

// ---------------- fused: softmax partials (blocks 0..1023) + CSR scan (block 1024) -----
__launch_bounds__(256)
__global__ void k_mid(const float* __restrict__ s, float* __restrict__ part,
                      const int* __restrict__ cnt, int* __restrict__ rowptr,
                      int* __restrict__ cursor)
{
    const int t = threadIdx.x;
    if (blockIdx.x < 1024) {
        const int n = NMAT + NEDGE;
        float mx = -INFINITY, sm = 0.f;
        for (int i = blockIdx.x * 256 + t; i < n; i += 1024 * 256) {
            float x = s[i];
            if (x > mx) { sm = sm * expf(mx - x) + 1.f; mx = x; }
            else        { sm += expf(x - mx); }
        }
#pragma unroll
        for (int off = 1; off < 64; off <<= 1) {
            float om = __shfl_xor(mx, off, 64);
            float os = __shfl_xor(sm, off, 64);
            float nm = fmaxf(mx, om);
            sm = sm * expf(mx - nm) + os * expf(om - nm);
            mx = nm;
        }
        __shared__ float wm[4], wsum[4];
        int lane = t & 63, wvi = t >> 6;
        if (lane == 0) { wm[wvi] = mx; wsum[wvi] = sm; }
        __syncthreads();
        if (t == 0) {
            float M = wm[0], S = wsum[0];
            for (int i = 1; i < 4; ++i) {
                float nm = fmaxf(M, wm[i]);
                S = S * expf(M - nm) + wsum[i] * expf(wm[i] - nm);
                M = nm;
            }
            part[2 * blockIdx.x]     = M;
            part[2 * blockIdx.x + 1] = S;
        }
    } else {
        __shared__ int sd[256];
        const int CH = 196;                          // 256*196 = 50176 >= 50000
        int base = t * CH;
        int lsum = 0;
        for (int j = 0; j < CH; ++j) {
            int idx = base + j;
            if (idx < NMAT) lsum += cnt[idx];
        }
        sd[t] = lsum;
        __syncthreads();
        for (int off = 1; off < 256; off <<= 1) {
            int v = (t >= off) ? sd[t - off] : 0;
            __syncthreads();
            sd[t] += v;
            __syncthreads();
        }
        int run = sd[t] - lsum;
        for (int j = 0; j < CH; ++j) {
            int idx = base + j;
            if (idx < NMAT) {
                rowptr[idx] = run;
                cursor[idx] = run;
                run += cnt[idx];
            }
        }
        if (t == 255) rowptr[NMAT] = NEDGE;
    }
}

// ---------------- final softmax merge ----------------
__launch_bounds__(256)
__global__ void softmax_red2(const float* __restrict__ part, float* __restrict__ stats)
{
    float mx = -INFINITY, sm = 0.f;
    for (int i = threadIdx.x; i < 1024; i += 256) {
        float M = part[2 * i], S = part[2 * i + 1];
        float nm = fmaxf(mx, M);
        sm = sm * expf(mx - nm) + S * expf(M - nm);
        mx = nm;
    }
#pragma unroll
    for (int off = 1; off < 64; off <<= 1) {
        float om = __shfl_xor(mx, off, 64);
        float os = __shfl_xor(sm, off, 64);
        float nm = fmaxf(mx, om);
        sm = sm * expf(mx - nm) + os * expf(om - nm);
        mx = nm;
    }
    __shared__ float wm[4], wsum[4];
    int lane = threadIdx.x & 63, wv = threadIdx.x >> 6;
    if (lane == 0) { wm[wv] = mx; wsum[wv] = sm; }
    __syncthreads();
    if (threadIdx.x == 0) {
        float M = wm[0], S = wsum[0];
        for (int i = 1; i < 4; ++i) {
            float nm = fmaxf(M, wm[i]);
            S = S * expf(M - nm) + wsum[i] * expf(wm[i] - nm);
            M = nm;
        }
        stats[0] = M;
        stats[1] = 1.f / S;
    }
}

// ---------------- fused CSR fill: wave per 16 edges, per-lane parallel atomics --------
// writes srcw[pos] = (src, w) and wea[pos][:] = bf16(w * edge_attr[e][:])
__launch_bounds__(256)
__global__ void k_fill2(const float* __restrict__ edge_attr,
                        const int* __restrict__ esrc, const int* __restrict__ edst,
                        const float* __restrict__ s, const float* __restrict__ stats,
                        int* __restrict__ cursor,
                        uint2* __restrict__ srcw, unsigned short* __restrict__ wea)
{
    const int t = threadIdx.x, w = t >> 6, l = t & 63, li = l & 15;
    const int chunk = blockIdx.x * 64 + w * 16;
    const float Mx = stats[0], invS = stats[1];

    int sv = 0, dv = 0; float scv = 0.f;
    if (l < 16) { sv = esrc[chunk + li]; dv = edst[chunk + li]; scv = s[NMAT + chunk + li]; }
    float wgt16 = expf(scv - Mx) * invS;
    int p = 0;
    if (l < 16) p = atomicAdd(&cursor[dv], 1);

#pragma unroll
    for (int i = 0; i < 16; ++i) {
        int   pos = __shfl(p, i, 64);
        float wg  = __shfl(wgt16, i, 64);
        int   src = __shfl(sv, i, 64);
        float av  = __builtin_nontemporal_load(edge_attr + (size_t)(chunk + i) * DEAT + l);
        __builtin_nontemporal_store(f2bf(wg * av), wea + (size_t)pos * DEAT + l);
        if (l == 0) srcw[pos] = make_uint2((unsigned)src, __float_as_uint(wg));
    }
}

// ---------------- CSR aggregate + fused epilogue ----------------
// wave per material: a = sum w*opb[src] (gather, LLC-hot) + stream wea; + (sum wea)@Wb
__launch_bounds__(256)
__global__ void k_agg(const unsigned short* __restrict__ opb,
                      const unsigned short* mb,            // NO restrict: aliases out
                      const unsigned short* __restrict__ wea,
                      const uint2* __restrict__ srcw,
                      const float* __restrict__ W_op, const float* __restrict__ s,
                      const float* __restrict__ stats, const int* __restrict__ rowptr,
                      float* out)                          // NO restrict: aliases mb
{
    __shared__ unsigned int Wb2[64 * 64];   // packed bf16 pairs of W_op rows 192..255 (16 KB)
    const int t = threadIdx.x;
#pragma unroll
    for (int it = 0; it < 16; ++it) {
        int q = t + 256 * it;
        int k = q >> 6, c2 = q & 63;
        float2 v = *reinterpret_cast<const float2*>(W_op + (size_t)(DOPR + k) * 128 + 2 * c2);
        Wb2[q] = (unsigned int)f2bf(v.x) | ((unsigned int)f2bf(v.y) << 16);
    }
    __syncthreads();

    const int w = t >> 6, l = t & 63;
    const int mid = blockIdx.x * 4 + w;
    const float Mx = stats[0], invS = stats[1];
    const int beg = rowptr[mid], end = rowptr[mid + 1];

    // read own mb row FIRST (out write later clobbers it)
    unsigned int mv = *reinterpret_cast<const unsigned int*>(mb + (size_t)mid * 256 + 2 * l);

    float a0 = 0.f, a1 = 0.f, aw = 0.f;
    int base = beg;
    for (; base + 8 <= end; base += 8) {
        uint2 mt[8];
#pragma unroll
        for (int u = 0; u < 8; ++u) mt[u] = srcw[base + u];        // uniform broadcast
        unsigned int o[8]; unsigned short ev[8];
#pragma unroll
        for (int u = 0; u < 8; ++u) {
            o[u]  = *reinterpret_cast<const unsigned int*>(opb + (size_t)mt[u].x * 128 + 2 * l);
            ev[u] = __builtin_nontemporal_load(wea + (size_t)(base + u) * DEAT + l);
        }
#pragma unroll
        for (int u = 0; u < 8; ++u) {
            float wg = __uint_as_float(mt[u].y);
            a0 += wg * bflo(o[u]); a1 += wg * bfhi(o[u]); aw += bf1(ev[u]);
        }
    }
    for (; base < end; ++base) {
        uint2 mt = srcw[base];
        unsigned int o = *reinterpret_cast<const unsigned int*>(opb + (size_t)mt.x * 128 + 2 * l);
        float wg = __uint_as_float(mt.y);
        a0 += wg * bflo(o); a1 += wg * bfhi(o);
        aw += bf1(__builtin_nontemporal_load(wea + (size_t)base * DEAT + l));
    }

    float acc0 = a0, acc1 = a1;
#pragma unroll
    for (int k = 0; k < 64; ++k) {
        float awk = __shfl(aw, k, 64);
        unsigned int wb = Wb2[k * 64 + l];
        acc0 += awk * bflo(wb);
        acc1 += awk * bfhi(wb);
    }
    float ns = expf(s[mid] - Mx) * invS;
    float2 r = {elu(ns * bflo(mv) + acc0), elu(ns * bfhi(mv) + acc1)};
    *reinterpret_cast<float2*>(out + (size_t)mid * 128 + 2 * l) = r;
}

extern "C" void kernel_launch(void* const* d_in, const int* in_sizes, int n_in,
                              void* d_out, int out_size, void* d_ws, size_t ws_size,
                              hipStream_t stream)
{
    const float* materials  = (const float*)d_in[0];
    const float* operations = (const float*)d_in[1];
    const float* edge_attr  = (const float*)d_in[2];
    const int*   esrc       = (const int*)d_in[3];
    const int*   edst       = (const int*)d_in[4];
    const float* W_mat      = (const float*)d_in[5];
    const float* W_op       = (const float*)d_in[6];
    const float* att_self   = (const float*)d_in[7];
    const float* att_cross  = (const float*)d_in[8];
    float* out = (float*)d_out;

    // bf16 m lives INSIDE d_out: row mid at byte 512*mid + 256 (stride 256 ushorts)
    unsigned short* mb = (unsigned short*)d_out + 128;

    char* p = (char*)d_ws;
    auto take = [&](size_t bytes) { char* r = p; p += (bytes + 255) & ~(size_t)255; return r; };

    unsigned short* opb     = (unsigned short*)take((size_t)NOPS * 128 * 2);   // 25.6 MB
    float*          s_buf   = (float*)take((size_t)(NMAT + NEDGE) * 4);        // 2.25 MB
    float*          dm      = (float*)take((size_t)NMAT * 4);
    float*          dop     = (float*)take((size_t)NOPS * 4);
    float*          asum    = (float*)take(128 * 4);
    float*          wv      = (float*)take(64 * 4);
    float*          wmc0    = (float*)take(128 * 4);
    float*          wmas    = (float*)take(128 * 4);
    float*          woc1    = (float*)take(DOPR * 4);
    unsigned short* BtM     = (unsigned short*)take(128 * 128 * 2);
    unsigned short* BtO     = (unsigned short*)take(128 * DOPR * 2);
    float*          part    = (float*)take(2048 * 4);
    float*          stats   = (float*)take(2 * 4);
    int*            cnt     = (int*)take((size_t)NMAT * 4);
    int*            rowptr  = (int*)take((size_t)(NMAT + 1) * 4);
    int*            cursor  = (int*)take((size_t)NMAT * 4);
    uint2*          srcw    = (uint2*)take((size_t)NEDGE * 8);                 // 4.1 MB
    unsigned short* wea     = (unsigned short*)take((size_t)NEDGE * DEAT * 2); // 65.5 MB
    (void)ws_size;

    hipMemsetAsync(cnt, 0, NMAT * sizeof(int), stream);

    k_prepconv<<<97, 256, 0, stream>>>(att_self, att_cross, W_mat, W_op,
                                       asum, wv, wmc0, wmas, woc1, BtM, BtO);
    gemm_mfma<128, 1><<<(NMAT + 127) / 128, 256, 0, stream>>>(
        materials, BtM, mb, 256, wmc0, wmas, dm, s_buf, NMAT);
    gemm_mfma<192, 2><<<(NOPS + 127) / 128, 256, 0, stream>>>(
        operations, BtO, opb, 128, woc1, nullptr, dop, nullptr, NOPS);
    k_edge_score<<<NEDGE / 128, 256, 0, stream>>>(edge_attr, esrc, edst, dm, dop, wv,
                                                  s_buf, cnt);
    k_mid<<<1025, 256, 0, stream>>>(s_buf, part, cnt, rowptr, cursor);
    softmax_red2<<<1, 256, 0, stream>>>(part, stats);
    k_fill2<<<NEDGE / 64, 256, 0, stream>>>(edge_attr, esrc, edst, s_buf, stats,
                                            cursor, srcw, wea);
    k_agg<<<NMAT / 4, 256, 0, stream>>>(opb, mb, wea, srcw, W_op, s_buf, stats,
                                        rowptr, out);
}

// Round 6
// 353.924 us; speedup vs baseline: 1.2100x; 1.2100x over previous
//
#include <hip/hip_runtime.h>
#include <hip/hip_bf16.h>
#include <math.h>

#define NMAT  50000
#define NOPS  100000
#define NEDGE 512000
#define DOPR  192
#define DEAT  64

typedef __attribute__((ext_vector_type(8))) short bfx8;
typedef __attribute__((ext_vector_type(4))) float fx4;

static __device__ __forceinline__ float lrelu(float x) { return x > 0.f ? x : 0.2f * x; }
static __device__ __forceinline__ float elu(float x)   { return x > 0.f ? x : expm1f(x); }
static __device__ __forceinline__ unsigned short f2bf(float x) {
    unsigned int b = __float_as_uint(x);
    return (unsigned short)((b + 0x7fffu + ((b >> 16) & 1u)) >> 16);   // RNE
}
static __device__ __forceinline__ float bflo(unsigned int u) { return __uint_as_float(u << 16); }
static __device__ __forceinline__ float bfhi(unsigned int u) { return __uint_as_float(u & 0xffff0000u); }
static __device__ __forceinline__ float bf1(unsigned short u) { return __uint_as_float(((unsigned int)u) << 16); }

// ---------------- prep (block 0) + weight bf16-transpose conv (blocks 1..96) ----------
__launch_bounds__(256)
__global__ void k_prepconv(const float* __restrict__ att_self, const float* __restrict__ att_cross,
                           const float* __restrict__ W_mat, const float* __restrict__ W_op,
                           float* __restrict__ asum, float* __restrict__ wv,
                           float* __restrict__ wmc0, float* __restrict__ wmas,
                           float* __restrict__ woc1,
                           unsigned short* __restrict__ BtM, unsigned short* __restrict__ BtO,
                           unsigned short* __restrict__ BtO2)
{
    const int b = blockIdx.x, t = threadIdx.x;
    if (b == 0) {
        __shared__ float as_sh[128];
        if (t < 128) { float v = att_self[t] + att_self[128 + t]; asum[t] = v; as_sh[t] = v; }
        __syncthreads();
        if (t < 128) {
            const float* wr = W_mat + (size_t)t * 128;
            float p0 = 0.f, p1 = 0.f;
            for (int j = 0; j < 128; ++j) { p0 += wr[j] * att_cross[j]; p1 += wr[j] * as_sh[j]; }
            wmc0[t] = p0; wmas[t] = p1;
        }
        const float* wr = W_op + (size_t)t * 128;
        float p = 0.f;
        for (int j = 0; j < 128; ++j) p += wr[j] * att_cross[128 + j];
        if (t < DOPR) woc1[t] = p; else wv[t - DOPR] = p;
    } else {
        int id = (b - 1) * 256 + t;
        if (id < 128 * 128) {
            int c = id >> 7, k = id & 127;
            BtM[c * 128 + k] = f2bf(W_mat[(size_t)k * 128 + c]);
        }
        if (id < 128 * DOPR) {
            int c = id / DOPR, k = id % DOPR;
            BtO[c * DOPR + k] = f2bf(W_op[(size_t)k * 128 + c]);
        }
        if (id < 128 * 64) {       // Wb^T for k_epi: BtO2[c][k2] = W_op[192+k2][c], stride 72
            int c = id >> 6, k = id & 63;
            BtO2[c * 72 + k] = f2bf(W_op[(size_t)(DOPR + k) * 128 + c]);
        }
    }
}

// ---------------- MFMA GEMM: Cb[M][cstride] = bf16(A[M][K] @ B), fused fp32 row-dots ----
// MODE 1: d1 = A.v1 (dm), d2 = lrelu(A.v2) (s_self).  MODE 2: d1 = A.v1 (dop).
template<int K, int MODE>
__launch_bounds__(256)
__global__ void gemm_mfma(const float* __restrict__ A, const unsigned short* __restrict__ Bt,
                          unsigned short* __restrict__ Cb, int cstride,
                          const float* __restrict__ v1, const float* __restrict__ v2,
                          float* __restrict__ d1, float* __restrict__ d2, int M)
{
    __shared__ unsigned short As[128 * 40];   // [row][k], stride 40
    __shared__ unsigned short Bs[128 * 40];   // [col][k]
    const int t = threadIdx.x;
    const int w = t >> 6, l = t & 63;
    const int lr = l & 15, lk = l >> 4;
    const int row0 = blockIdx.x * 128;

    fx4 acc[2][8];
#pragma unroll
    for (int i = 0; i < 2; ++i)
#pragma unroll
        for (int j = 0; j < 8; ++j) acc[i][j] = (fx4){0.f, 0.f, 0.f, 0.f};
    float pd1[4] = {0.f, 0.f, 0.f, 0.f};
    float pd2[4] = {0.f, 0.f, 0.f, 0.f};

    for (int k0 = 0; k0 < K; k0 += 32) {
#pragma unroll
        for (int it = 0; it < 4; ++it) {             // stage A (fp32 -> bf16) + dot partials
            int q  = t + 256 * it;
            int r  = q >> 3;
            int kk = (q & 7) * 4;
            int gr = row0 + r; if (gr >= M) gr = M - 1;
            float4 v = *reinterpret_cast<const float4*>(A + (size_t)gr * K + k0 + kk);
            ushort4 bb = {f2bf(v.x), f2bf(v.y), f2bf(v.z), f2bf(v.w)};
            *reinterpret_cast<ushort4*>(&As[r * 40 + kk]) = bb;
            pd1[it] += v.x * v1[k0 + kk] + v.y * v1[k0 + kk + 1]
                     + v.z * v1[k0 + kk + 2] + v.w * v1[k0 + kk + 3];
            if (MODE == 1)
                pd2[it] += v.x * v2[k0 + kk] + v.y * v2[k0 + kk + 1]
                         + v.z * v2[k0 + kk + 2] + v.w * v2[k0 + kk + 3];
        }
#pragma unroll
        for (int it = 0; it < 2; ++it) {             // stage B chunk (bf16, pre-transposed)
            int q  = t + 256 * it;
            int c  = q >> 2;
            int kg = (q & 3) * 8;
            uint4 vb = *reinterpret_cast<const uint4*>(&Bt[(size_t)c * K + k0 + kg]);
            *reinterpret_cast<uint4*>(&Bs[c * 40 + kg]) = vb;
        }
        __syncthreads();
        bfx8 af0 = *reinterpret_cast<const bfx8*>(&As[(w * 32 + lr) * 40 + lk * 8]);
        bfx8 af1 = *reinterpret_cast<const bfx8*>(&As[(w * 32 + 16 + lr) * 40 + lk * 8]);
#pragma unroll
        for (int ni = 0; ni < 8; ++ni) {
            bfx8 bf = *reinterpret_cast<const bfx8*>(&Bs[(ni * 16 + lr) * 40 + lk * 8]);
            acc[0][ni] = __builtin_amdgcn_mfma_f32_16x16x32_bf16(af0, bf, acc[0][ni], 0, 0, 0);
            acc[1][ni] = __builtin_amdgcn_mfma_f32_16x16x32_bf16(af1, bf, acc[1][ni], 0, 0, 0);
        }
        __syncthreads();
    }

    // C/D layout: col = lane&15, row = (lane>>4)*4 + reg
#pragma unroll
    for (int mi = 0; mi < 2; ++mi)
#pragma unroll
        for (int ni = 0; ni < 8; ++ni)
#pragma unroll
            for (int r2 = 0; r2 < 4; ++r2) {
                int row = row0 + w * 32 + mi * 16 + lk * 4 + r2;
                int col = ni * 16 + lr;
                if (row < M) Cb[(size_t)row * cstride + col] = f2bf(acc[mi][ni][r2]);
            }

    // fused row dots: 8 consecutive threads share one tile row
#pragma unroll
    for (int it = 0; it < 4; ++it) {
        float p1 = pd1[it], p2 = pd2[it];
#pragma unroll
        for (int off = 1; off < 8; off <<= 1) {
            p1 += __shfl_xor(p1, off, 8);
            if (MODE == 1) p2 += __shfl_xor(p2, off, 8);
        }
        int r  = (t + 256 * it) >> 3;
        int gr = row0 + r;
        if ((t & 7) == 0 && gr < M) {
            d1[gr] = p1;
            if (MODE == 1) d2[gr] = lrelu(p2);
        }
    }
}

// ---------------- edge scores + dst histogram + bf16 edge_attr copy ----------------
__launch_bounds__(256)
__global__ void k_edge_score(const float* __restrict__ edge_attr,
                             const int* __restrict__ esrc, const int* __restrict__ edst,
                             const float* __restrict__ dm, const float* __restrict__ dop,
                             const float* __restrict__ wv, float* __restrict__ s,
                             int* __restrict__ cnt, unsigned short* __restrict__ eab)
{
    int t = threadIdx.x;
    int g = t >> 4, q = t & 15;
    float4 wvq = *reinterpret_cast<const float4*>(wv + q * 4);
#pragma unroll
    for (int u = 0; u < 8; ++u) {
        int e = blockIdx.x * 128 + u * 16 + g;
        float4 av = *reinterpret_cast<const float4*>(edge_attr + (size_t)e * DEAT + q * 4);
        ushort4 bb = {f2bf(av.x), f2bf(av.y), f2bf(av.z), f2bf(av.w)};
        *reinterpret_cast<ushort4*>(&eab[(size_t)e * DEAT + q * 4]) = bb;
        float p = av.x * wvq.x + av.y * wvq.y + av.z * wvq.z + av.w * wvq.w;
#pragma unroll
        for (int off = 1; off < 16; off <<= 1) p += __shfl_xor(p, off, 16);
        if (q == 0) {
            int d = edst[e];
            s[NMAT + e] = lrelu(p + dm[d] + dop[esrc[e]]);
            atomicAdd(&cnt[d], 1);
        }
    }
}

// ---------------- fused: softmax partials (blocks 0..1023) + CSR scan (block 1024) -----
__launch_bounds__(256)
__global__ void k_mid(const float* __restrict__ s, float* __restrict__ part,
                      const int* __restrict__ cnt, int* __restrict__ rowptr,
                      int* __restrict__ cursor)
{
    const int t = threadIdx.x;
    if (blockIdx.x < 1024) {
        const int n = NMAT + NEDGE;
        float mx = -INFINITY, sm = 0.f;
        for (int i = blockIdx.x * 256 + t; i < n; i += 1024 * 256) {
            float x = s[i];
            if (x > mx) { sm = sm * expf(mx - x) + 1.f; mx = x; }
            else        { sm += expf(x - mx); }
        }
#pragma unroll
        for (int off = 1; off < 64; off <<= 1) {
            float om = __shfl_xor(mx, off, 64);
            float os = __shfl_xor(sm, off, 64);
            float nm = fmaxf(mx, om);
            sm = sm * expf(mx - nm) + os * expf(om - nm);
            mx = nm;
        }
        __shared__ float wm[4], wsum[4];
        int lane = t & 63, wvi = t >> 6;
        if (lane == 0) { wm[wvi] = mx; wsum[wvi] = sm; }
        __syncthreads();
        if (t == 0) {
            float M = wm[0], S = wsum[0];
            for (int i = 1; i < 4; ++i) {
                float nm = fmaxf(M, wm[i]);
                S = S * expf(M - nm) + wsum[i] * expf(wm[i] - nm);
                M = nm;
            }
            part[2 * blockIdx.x]     = M;
            part[2 * blockIdx.x + 1] = S;
        }
    } else {
        __shared__ int sd[256];
        const int CH = 196;                          // 256*196 = 50176 >= 50000
        int base = t * CH;
        int lsum = 0;
        for (int j = 0; j < CH; ++j) {
            int idx = base + j;
            if (idx < NMAT) lsum += cnt[idx];
        }
        sd[t] = lsum;
        __syncthreads();
        for (int off = 1; off < 256; off <<= 1) {
            int v = (t >= off) ? sd[t - off] : 0;
            __syncthreads();
            sd[t] += v;
            __syncthreads();
        }
        int run = sd[t] - lsum;
        for (int j = 0; j < CH; ++j) {
            int idx = base + j;
            if (idx < NMAT) {
                rowptr[idx] = run;
                cursor[idx] = run;
                run += cnt[idx];
            }
        }
        if (t == 255) rowptr[NMAT] = NEDGE;
    }
}

// ---------------- final softmax merge ----------------
__launch_bounds__(256)
__global__ void softmax_red2(const float* __restrict__ part, float* __restrict__ stats)
{
    float mx = -INFINITY, sm = 0.f;
    for (int i = threadIdx.x; i < 1024; i += 256) {
        float M = part[2 * i], S = part[2 * i + 1];
        float nm = fmaxf(mx, M);
        sm = sm * expf(mx - nm) + S * expf(M - nm);
        mx = nm;
    }
#pragma unroll
    for (int off = 1; off < 64; off <<= 1) {
        float om = __shfl_xor(mx, off, 64);
        float os = __shfl_xor(sm, off, 64);
        float nm = fmaxf(mx, om);
        sm = sm * expf(mx - nm) + os * expf(om - nm);
        mx = nm;
    }
    __shared__ float wm[4], wsum[4];
    int lane = threadIdx.x & 63, wv = threadIdx.x >> 6;
    if (lane == 0) { wm[wv] = mx; wsum[wv] = sm; }
    __syncthreads();
    if (threadIdx.x == 0) {
        float M = wm[0], S = wsum[0];
        for (int i = 1; i < 4; ++i) {
            float nm = fmaxf(M, wm[i]);
            S = S * expf(M - nm) + wsum[i] * expf(wm[i] - nm);
            M = nm;
        }
        stats[0] = M;
        stats[1] = 1.f / S;
    }
}

// ---------------- CSR fill ----------------
__launch_bounds__(256)
__global__ void k_fill(const int* __restrict__ edst, int* __restrict__ cursor,
                       int* __restrict__ eid)
{
    int e = blockIdx.x * 256 + threadIdx.x;
    if (e >= NEDGE) return;
    int pos = atomicAdd(&cursor[edst[e]], 1);
    eid[pos] = e;
}

// ---------------- CSR metadata (streaming, coalesced writes) ----------------
__launch_bounds__(256)
__global__ void k_csrmeta(const int* __restrict__ eid, const int* __restrict__ esrc,
                          const float* __restrict__ s, const float* __restrict__ stats,
                          int* __restrict__ src_csr, float* __restrict__ w_csr)
{
    int i = blockIdx.x * 256 + threadIdx.x;
    if (i >= NEDGE) return;
    int e = eid[i];
    src_csr[i] = esrc[e];
    w_csr[i] = expf(s[NMAT + e] - stats[0]) * stats[1];
}

// ---------------- CSR aggregate (no LDS, no Wb epilogue) ----------------
// wave per material: a = sum w*opb[src], aw = sum w*eab[e]
// writes awb[mid][64] bf16 and partial = ns*m + ap into out (fp32, overwritten by k_epi)
__launch_bounds__(256)
__global__ void k_agg(const unsigned short* __restrict__ opb,
                      const unsigned short* mb,            // NO restrict: aliases out
                      const unsigned short* __restrict__ eab,
                      const int* __restrict__ eid, const int* __restrict__ src_csr,
                      const float* __restrict__ w_csr,
                      const float* __restrict__ s, const float* __restrict__ stats,
                      const int* __restrict__ rowptr,
                      unsigned short* __restrict__ awb, float* out)   // out aliases mb
{
    const int t = threadIdx.x;
    const int w = t >> 6, l = t & 63;
    const int mid = blockIdx.x * 4 + w;
    const float Mx = stats[0], invS = stats[1];
    const int beg = rowptr[mid], end = rowptr[mid + 1];

    // read own mb row FIRST (partial write below clobbers it)
    unsigned int mv = *reinterpret_cast<const unsigned int*>(mb + (size_t)mid * 256 + 2 * l);

    float a0 = 0.f, a1 = 0.f, aw = 0.f;
    int base = beg;
    for (; base + 8 <= end; base += 8) {
        int ee[8], ss[8]; float ww[8];
#pragma unroll
        for (int u = 0; u < 8; ++u) {
            ee[u] = eid[base + u]; ss[u] = src_csr[base + u]; ww[u] = w_csr[base + u];
        }
        unsigned int o[8]; unsigned short ev[8];
#pragma unroll
        for (int u = 0; u < 8; ++u) {
            o[u]  = *reinterpret_cast<const unsigned int*>(opb + (size_t)ss[u] * 128 + 2 * l);
            ev[u] = eab[(size_t)ee[u] * DEAT + l];
        }
#pragma unroll
        for (int u = 0; u < 8; ++u) {
            a0 += ww[u] * bflo(o[u]); a1 += ww[u] * bfhi(o[u]); aw += ww[u] * bf1(ev[u]);
        }
    }
    for (; base < end; ++base) {
        int e = eid[base], src = src_csr[base];
        float wg = w_csr[base];
        unsigned int o = *reinterpret_cast<const unsigned int*>(opb + (size_t)src * 128 + 2 * l);
        a0 += wg * bflo(o); a1 += wg * bfhi(o);
        aw += wg * bf1(eab[(size_t)e * DEAT + l]);
    }

    awb[(size_t)mid * 64 + l] = f2bf(aw);
    float ns = expf(s[mid] - Mx) * invS;
    float2 r = {ns * bflo(mv) + a0, ns * bfhi(mv) + a1};
    *reinterpret_cast<float2*>(out + (size_t)mid * 128 + 2 * l) = r;
}

// ---------------- MFMA epilogue: out = elu(partial + awb @ Wb), in-place on out -------
__launch_bounds__(256)
__global__ void k_epi(const unsigned short* __restrict__ awb,
                      const unsigned short* __restrict__ BtO2,   // [128][72] bf16 Wb^T
                      float* __restrict__ out)
{
    __shared__ unsigned short Bs[128 * 72];   // 18 KB, [col][k] stride 72
    const int t = threadIdx.x;
#pragma unroll
    for (int it = 0; it < 9; ++it) {
        int q = t + 256 * it;
        reinterpret_cast<uint4*>(Bs)[q] = reinterpret_cast<const uint4*>(BtO2)[q];
    }
    __syncthreads();

    const int w = t >> 6, l = t & 63, lr = l & 15, lk = l >> 4;
    const int row0 = blockIdx.x * 64 + w * 16;

    fx4 acc[8];
#pragma unroll
    for (int ni = 0; ni < 8; ++ni) acc[ni] = (fx4){0.f, 0.f, 0.f, 0.f};

#pragma unroll
    for (int k0 = 0; k0 < 64; k0 += 32) {
        int ar = row0 + lr; if (ar >= NMAT) ar = NMAT - 1;
        bfx8 af = *reinterpret_cast<const bfx8*>(awb + (size_t)ar * 64 + k0 + lk * 8);
#pragma unroll
        for (int ni = 0; ni < 8; ++ni) {
            bfx8 bf = *reinterpret_cast<const bfx8*>(&Bs[(ni * 16 + lr) * 72 + k0 + lk * 8]);
            acc[ni] = __builtin_amdgcn_mfma_f32_16x16x32_bf16(af, bf, acc[ni], 0, 0, 0);
        }
    }

    // C/D: col = ni*16 + (lane&15), row = (lane>>4)*4 + reg
#pragma unroll
    for (int ni = 0; ni < 8; ++ni)
#pragma unroll
        for (int r2 = 0; r2 < 4; ++r2) {
            int gr = row0 + lk * 4 + r2;
            if (gr < NMAT) {
                size_t idx = (size_t)gr * 128 + ni * 16 + lr;
                out[idx] = elu(out[idx] + acc[ni][r2]);
            }
        }
}

extern "C" void kernel_launch(void* const* d_in, const int* in_sizes, int n_in,
                              void* d_out, int out_size, void* d_ws, size_t ws_size,
                              hipStream_t stream)
{
    const float* materials  = (const float*)d_in[0];
    const float* operations = (const float*)d_in[1];
    const float* edge_attr  = (const float*)d_in[2];
    const int*   esrc       = (const int*)d_in[3];
    const int*   edst       = (const int*)d_in[4];
    const float* W_mat      = (const float*)d_in[5];
    const float* W_op       = (const float*)d_in[6];
    const float* att_self   = (const float*)d_in[7];
    const float* att_cross  = (const float*)d_in[8];
    float* out = (float*)d_out;

    // bf16 m lives inside d_out second row-halves: row mid at ushort offset mid*256 + 128
    unsigned short* mb = (unsigned short*)d_out + 128;

    char* p = (char*)d_ws;
    auto take = [&](size_t bytes) { char* r = p; p += (bytes + 255) & ~(size_t)255; return r; };

    unsigned short* opb     = (unsigned short*)take((size_t)NOPS * 128 * 2);   // 25.6 MB
    float*          s_buf   = (float*)take((size_t)(NMAT + NEDGE) * 4);        // 2.25 MB
    float*          dm      = (float*)take((size_t)NMAT * 4);
    float*          dop     = (float*)take((size_t)NOPS * 4);
    float*          asum    = (float*)take(128 * 4);
    float*          wv      = (float*)take(64 * 4);
    float*          wmc0    = (float*)take(128 * 4);
    float*          wmas    = (float*)take(128 * 4);
    float*          woc1    = (float*)take(DOPR * 4);
    unsigned short* BtM     = (unsigned short*)take(128 * 128 * 2);
    unsigned short* BtO     = (unsigned short*)take(128 * DOPR * 2);
    unsigned short* BtO2    = (unsigned short*)take(128 * 72 * 2);
    float*          part    = (float*)take(2048 * 4);
    float*          stats   = (float*)take(2 * 4);
    int*            cnt     = (int*)take((size_t)NMAT * 4);
    int*            rowptr  = (int*)take((size_t)(NMAT + 1) * 4);
    int*            cursor  = (int*)take((size_t)NMAT * 4);
    int*            eid     = (int*)take((size_t)NEDGE * 4);                   // 2.05 MB
    int*            src_csr = (int*)take((size_t)NEDGE * 4);                   // 2.05 MB
    float*          w_csr   = (float*)take((size_t)NEDGE * 4);                 // 2.05 MB
    unsigned short* eab     = (unsigned short*)take((size_t)NEDGE * DEAT * 2); // 65.5 MB
    unsigned short* awb     = (unsigned short*)take((size_t)NMAT * 64 * 2);    // 6.4 MB
    (void)ws_size;                                                             // ~107 MB total

    hipMemsetAsync(cnt, 0, NMAT * sizeof(int), stream);

    k_prepconv<<<97, 256, 0, stream>>>(att_self, att_cross, W_mat, W_op,
                                       asum, wv, wmc0, wmas, woc1, BtM, BtO, BtO2);
    gemm_mfma<128, 1><<<(NMAT + 127) / 128, 256, 0, stream>>>(
        materials, BtM, mb, 256, wmc0, wmas, dm, s_buf, NMAT);
    gemm_mfma<192, 2><<<(NOPS + 127) / 128, 256, 0, stream>>>(
        operations, BtO, opb, 128, woc1, nullptr, dop, nullptr, NOPS);
    k_edge_score<<<NEDGE / 128, 256, 0, stream>>>(edge_attr, esrc, edst, dm, dop, wv,
                                                  s_buf, cnt, eab);
    k_mid<<<1025, 256, 0, stream>>>(s_buf, part, cnt, rowptr, cursor);
    softmax_red2<<<1, 256, 0, stream>>>(part, stats);
    k_fill<<<NEDGE / 256, 256, 0, stream>>>(edst, cursor, eid);
    k_csrmeta<<<NEDGE / 256, 256, 0, stream>>>(eid, esrc, s_buf, stats, src_csr, w_csr);
    k_agg<<<NMAT / 4, 256, 0, stream>>>(opb, mb, eab, eid, src_csr, w_csr,
                                        s_buf, stats, rowptr, awb, out);
    k_epi<<<(NMAT + 63) / 64, 256, 0, stream>>>(awb, BtO2, out);
}

// Round 7
// 214.389 us; speedup vs baseline: 1.9976x; 1.6509x over previous
//
#include <hip/hip_runtime.h>
#include <hip/hip_bf16.h>
#include <math.h>

#define NMAT  50000
#define NOPS  100000
#define NEDGE 512000
#define DOPR  192
#define DEAT  64

typedef __attribute__((ext_vector_type(8))) short bfx8;
typedef __attribute__((ext_vector_type(4))) float fx4;

static __device__ __forceinline__ float lrelu(float x) { return x > 0.f ? x : 0.2f * x; }
static __device__ __forceinline__ float elu(float x)   { return x > 0.f ? x : expm1f(x); }
static __device__ __forceinline__ unsigned short f2bf(float x) {
    unsigned int b = __float_as_uint(x);
    return (unsigned short)((b + 0x7fffu + ((b >> 16) & 1u)) >> 16);   // RNE
}
static __device__ __forceinline__ float bflo(unsigned int u) { return __uint_as_float(u << 16); }
static __device__ __forceinline__ float bfhi(unsigned int u) { return __uint_as_float(u & 0xffff0000u); }
static __device__ __forceinline__ float bf1(unsigned short u) { return __uint_as_float(((unsigned int)u) << 16); }

// ---------------- prep (block 0) + weight bf16-transpose conv (blocks 1..96) ----------
__launch_bounds__(256)
__global__ void k_prepconv(const float* __restrict__ att_self, const float* __restrict__ att_cross,
                           const float* __restrict__ W_mat, const float* __restrict__ W_op,
                           float* __restrict__ asum, float* __restrict__ wv,
                           float* __restrict__ wmc0, float* __restrict__ wmas,
                           float* __restrict__ woc1,
                           unsigned short* __restrict__ BtM, unsigned short* __restrict__ BtO,
                           unsigned short* __restrict__ BtO2)
{
    const int b = blockIdx.x, t = threadIdx.x;
    if (b == 0) {
        __shared__ float as_sh[128];
        if (t < 128) { float v = att_self[t] + att_self[128 + t]; asum[t] = v; as_sh[t] = v; }
        __syncthreads();
        if (t < 128) {
            const float* wr = W_mat + (size_t)t * 128;
            float p0 = 0.f, p1 = 0.f;
            for (int j = 0; j < 128; ++j) { p0 += wr[j] * att_cross[j]; p1 += wr[j] * as_sh[j]; }
            wmc0[t] = p0; wmas[t] = p1;
        }
        const float* wr = W_op + (size_t)t * 128;
        float p = 0.f;
        for (int j = 0; j < 128; ++j) p += wr[j] * att_cross[128 + j];
        if (t < DOPR) woc1[t] = p; else wv[t - DOPR] = p;
    } else {
        int id = (b - 1) * 256 + t;
        if (id < 128 * 128) {
            int c = id >> 7, k = id & 127;
            BtM[c * 128 + k] = f2bf(W_mat[(size_t)k * 128 + c]);
        }
        if (id < 128 * DOPR) {
            int c = id / DOPR, k = id % DOPR;
            BtO[c * DOPR + k] = f2bf(W_op[(size_t)k * 128 + c]);
        }
        if (id < 128 * 64) {       // Wb^T for k_epi: BtO2[c][k2] = W_op[192+k2][c], stride 72
            int c = id >> 6, k = id & 63;
            BtO2[c * 72 + k] = f2bf(W_op[(size_t)(DOPR + k) * 128 + c]);
        }
    }
}

// ---------------- MFMA GEMM: Cb[M][cstride] = bf16(A[M][K] @ B), fused fp32 row-dots ----
// MODE 1: d1 = A.v1 (dm), d2 = lrelu(A.v2) (s_self).  MODE 2: d1 = A.v1 (dop).
template<int K, int MODE>
__launch_bounds__(256)
__global__ void gemm_mfma(const float* __restrict__ A, const unsigned short* __restrict__ Bt,
                          unsigned short* __restrict__ Cb, int cstride,
                          const float* __restrict__ v1, const float* __restrict__ v2,
                          float* __restrict__ d1, float* __restrict__ d2, int M)
{
    __shared__ unsigned short As[128 * 40];   // [row][k], stride 40
    __shared__ unsigned short Bs[128 * 40];   // [col][k]
    const int t = threadIdx.x;
    const int w = t >> 6, l = t & 63;
    const int lr = l & 15, lk = l >> 4;
    const int row0 = blockIdx.x * 128;

    fx4 acc[2][8];
#pragma unroll
    for (int i = 0; i < 2; ++i)
#pragma unroll
        for (int j = 0; j < 8; ++j) acc[i][j] = (fx4){0.f, 0.f, 0.f, 0.f};
    float pd1[4] = {0.f, 0.f, 0.f, 0.f};
    float pd2[4] = {0.f, 0.f, 0.f, 0.f};

    for (int k0 = 0; k0 < K; k0 += 32) {
#pragma unroll
        for (int it = 0; it < 4; ++it) {             // stage A (fp32 -> bf16) + dot partials
            int q  = t + 256 * it;
            int r  = q >> 3;
            int kk = (q & 7) * 4;
            int gr = row0 + r; if (gr >= M) gr = M - 1;
            float4 v = *reinterpret_cast<const float4*>(A + (size_t)gr * K + k0 + kk);
            ushort4 bb = {f2bf(v.x), f2bf(v.y), f2bf(v.z), f2bf(v.w)};
            *reinterpret_cast<ushort4*>(&As[r * 40 + kk]) = bb;
            pd1[it] += v.x * v1[k0 + kk] + v.y * v1[k0 + kk + 1]
                     + v.z * v1[k0 + kk + 2] + v.w * v1[k0 + kk + 3];
            if (MODE == 1)
                pd2[it] += v.x * v2[k0 + kk] + v.y * v2[k0 + kk + 1]
                         + v.z * v2[k0 + kk + 2] + v.w * v2[k0 + kk + 3];
        }
#pragma unroll
        for (int it = 0; it < 2; ++it) {             // stage B chunk (bf16, pre-transposed)
            int q  = t + 256 * it;
            int c  = q >> 2;
            int kg = (q & 3) * 8;
            uint4 vb = *reinterpret_cast<const uint4*>(&Bt[(size_t)c * K + k0 + kg]);
            *reinterpret_cast<uint4*>(&Bs[c * 40 + kg]) = vb;
        }
        __syncthreads();
        bfx8 af0 = *reinterpret_cast<const bfx8*>(&As[(w * 32 + lr) * 40 + lk * 8]);
        bfx8 af1 = *reinterpret_cast<const bfx8*>(&As[(w * 32 + 16 + lr) * 40 + lk * 8]);
#pragma unroll
        for (int ni = 0; ni < 8; ++ni) {
            bfx8 bf = *reinterpret_cast<const bfx8*>(&Bs[(ni * 16 + lr) * 40 + lk * 8]);
            acc[0][ni] = __builtin_amdgcn_mfma_f32_16x16x32_bf16(af0, bf, acc[0][ni], 0, 0, 0);
            acc[1][ni] = __builtin_amdgcn_mfma_f32_16x16x32_bf16(af1, bf, acc[1][ni], 0, 0, 0);
        }
        __syncthreads();
    }

    // C/D layout: col = lane&15, row = (lane>>4)*4 + reg
#pragma unroll
    for (int mi = 0; mi < 2; ++mi)
#pragma unroll
        for (int ni = 0; ni < 8; ++ni)
#pragma unroll
            for (int r2 = 0; r2 < 4; ++r2) {
                int row = row0 + w * 32 + mi * 16 + lk * 4 + r2;
                int col = ni * 16 + lr;
                if (row < M) Cb[(size_t)row * cstride + col] = f2bf(acc[mi][ni][r2]);
            }

    // fused row dots: 8 consecutive threads share one tile row
#pragma unroll
    for (int it = 0; it < 4; ++it) {
        float p1 = pd1[it], p2 = pd2[it];
#pragma unroll
        for (int off = 1; off < 8; off <<= 1) {
            p1 += __shfl_xor(p1, off, 8);
            if (MODE == 1) p2 += __shfl_xor(p2, off, 8);
        }
        int r  = (t + 256 * it) >> 3;
        int gr = row0 + r;
        if ((t & 7) == 0 && gr < M) {
            d1[gr] = p1;
            if (MODE == 1) d2[gr] = lrelu(p2);
        }
    }
}

// ---------------- edge scores + dst histogram + bf16 edge_attr copy ----------------
__launch_bounds__(256)
__global__ void k_edge_score(const float* __restrict__ edge_attr,
                             const int* __restrict__ esrc, const int* __restrict__ edst,
                             const float* __restrict__ dm, const float* __restrict__ dop,
                             const float* __restrict__ wv, float* __restrict__ s,
                             int* __restrict__ cnt, unsigned short* __restrict__ eab)
{
    int t = threadIdx.x;
    int g = t >> 4, q = t & 15;
    float4 wvq = *reinterpret_cast<const float4*>(wv + q * 4);
#pragma unroll
    for (int u = 0; u < 8; ++u) {
        int e = blockIdx.x * 128 + u * 16 + g;
        float4 av = *reinterpret_cast<const float4*>(edge_attr + (size_t)e * DEAT + q * 4);
        ushort4 bb = {f2bf(av.x), f2bf(av.y), f2bf(av.z), f2bf(av.w)};
        *reinterpret_cast<ushort4*>(&eab[(size_t)e * DEAT + q * 4]) = bb;
        float p = av.x * wvq.x + av.y * wvq.y + av.z * wvq.z + av.w * wvq.w;
#pragma unroll
        for (int off = 1; off < 16; off <<= 1) p += __shfl_xor(p, off, 16);
        if (q == 0) {
            int d = edst[e];
            s[NMAT + e] = lrelu(p + dm[d] + dop[esrc[e]]);
            atomicAdd(&cnt[d], 1);
        }
    }
}

// ------- fused: softmax partials (blocks 0..1023) + block-local scans (1024..1219) ----
__launch_bounds__(256)
__global__ void k_mid2(const float* __restrict__ s, float* __restrict__ part,
                       const int* __restrict__ cnt, int* __restrict__ loc,
                       int* __restrict__ bsum)
{
    const int t = threadIdx.x;
    if (blockIdx.x < 1024) {
        const int n = NMAT + NEDGE;
        float mx = -INFINITY, sm = 0.f;
        for (int i = blockIdx.x * 256 + t; i < n; i += 1024 * 256) {
            float x = s[i];
            if (x > mx) { sm = sm * expf(mx - x) + 1.f; mx = x; }
            else        { sm += expf(x - mx); }
        }
#pragma unroll
        for (int off = 1; off < 64; off <<= 1) {
            float om = __shfl_xor(mx, off, 64);
            float os = __shfl_xor(sm, off, 64);
            float nm = fmaxf(mx, om);
            sm = sm * expf(mx - nm) + os * expf(om - nm);
            mx = nm;
        }
        __shared__ float wm[4], wsum[4];
        int lane = t & 63, wvi = t >> 6;
        if (lane == 0) { wm[wvi] = mx; wsum[wvi] = sm; }
        __syncthreads();
        if (t == 0) {
            float M = wm[0], S = wsum[0];
            for (int i = 1; i < 4; ++i) {
                float nm = fmaxf(M, wm[i]);
                S = S * expf(M - nm) + wsum[i] * expf(wm[i] - nm);
                M = nm;
            }
            part[2 * blockIdx.x]     = M;
            part[2 * blockIdx.x + 1] = S;
        }
    } else {
        // 256-element block scan of cnt
        const int b = blockIdx.x - 1024;                 // 0..195
        const int idx = b * 256 + t;
        int v = (idx < NMAT) ? cnt[idx] : 0;
        __shared__ int sd[256];
        sd[t] = v;
        __syncthreads();
#pragma unroll
        for (int off = 1; off < 256; off <<= 1) {
            int x = (t >= off) ? sd[t - off] : 0;
            __syncthreads();
            sd[t] += x;
            __syncthreads();
        }
        if (idx < NMAT) loc[idx] = sd[t] - v;            // local exclusive
        if (t == 255) bsum[b] = sd[t];
    }
}

// ---------------- final softmax merge + block-sum scan ----------------
__launch_bounds__(256)
__global__ void k_fin(const float* __restrict__ part, float* __restrict__ stats,
                      const int* __restrict__ bsum, int* __restrict__ boff)
{
    const int t = threadIdx.x;
    float mx = -INFINITY, sm = 0.f;
    for (int i = t; i < 1024; i += 256) {
        float M = part[2 * i], S = part[2 * i + 1];
        float nm = fmaxf(mx, M);
        sm = sm * expf(mx - nm) + S * expf(M - nm);
        mx = nm;
    }
#pragma unroll
    for (int off = 1; off < 64; off <<= 1) {
        float om = __shfl_xor(mx, off, 64);
        float os = __shfl_xor(sm, off, 64);
        float nm = fmaxf(mx, om);
        sm = sm * expf(mx - nm) + os * expf(om - nm);
        mx = nm;
    }
    __shared__ float wm[4], wsum[4];
    int lane = t & 63, wv = t >> 6;
    if (lane == 0) { wm[wv] = mx; wsum[wv] = sm; }
    __syncthreads();
    if (t == 0) {
        float M = wm[0], S = wsum[0];
        for (int i = 1; i < 4; ++i) {
            float nm = fmaxf(M, wm[i]);
            S = S * expf(M - nm) + wsum[i] * expf(wm[i] - nm);
            M = nm;
        }
        stats[0] = M;
        stats[1] = 1.f / S;
    }
    // exclusive scan of bsum[196]
    int v = (t < 196) ? bsum[t] : 0;
    __shared__ int sd[256];
    sd[t] = v;
    __syncthreads();
#pragma unroll
    for (int off = 1; off < 256; off <<= 1) {
        int x = (t >= off) ? sd[t - off] : 0;
        __syncthreads();
        sd[t] += x;
        __syncthreads();
    }
    if (t < 196) boff[t] = sd[t] - v;
}

// ---------------- scan phase C: rowptr/cursor = loc + boff ----------------
__launch_bounds__(256)
__global__ void k_scanC(const int* __restrict__ loc, const int* __restrict__ boff,
                        int* __restrict__ rowptr, int* __restrict__ cursor)
{
    int idx = blockIdx.x * 256 + threadIdx.x;
    if (idx < NMAT) {
        int r = loc[idx] + boff[blockIdx.x];
        rowptr[idx] = r;
        cursor[idx] = r;
    }
    if (idx == 0) rowptr[NMAT] = NEDGE;
}

// ---------------- fused CSR fill + metadata ----------------
__launch_bounds__(256)
__global__ void k_fill(const int* __restrict__ esrc, const int* __restrict__ edst,
                       const float* __restrict__ s, const float* __restrict__ stats,
                       int* __restrict__ cursor, int* __restrict__ eid,
                       int* __restrict__ src_csr, float* __restrict__ w_csr)
{
    int e = blockIdx.x * 256 + threadIdx.x;
    if (e >= NEDGE) return;
    float wg = expf(s[NMAT + e] - stats[0]) * stats[1];
    int pos = atomicAdd(&cursor[edst[e]], 1);
    eid[pos] = e;
    src_csr[pos] = esrc[e];
    w_csr[pos] = wg;
}

// ---------------- CSR aggregate (masked 8-wide, no LDS) ----------------
// wave per material: a = sum w*opb[src], aw = sum w*eab[e]
// writes awb[mid][64] bf16 and partial = ns*m + ap into out (fp32, finished by k_epi)
__launch_bounds__(256)
__global__ void k_agg(const unsigned short* __restrict__ opb,
                      const unsigned short* mb,            // NO restrict: aliases out
                      const unsigned short* __restrict__ eab,
                      const int* __restrict__ eid, const int* __restrict__ src_csr,
                      const float* __restrict__ w_csr,
                      const float* __restrict__ s, const float* __restrict__ stats,
                      const int* __restrict__ rowptr,
                      unsigned short* __restrict__ awb, float* out)   // out aliases mb
{
    const int t = threadIdx.x;
    const int w = t >> 6, l = t & 63;
    const int mid = blockIdx.x * 4 + w;
    const float Mx = stats[0], invS = stats[1];
    const int beg = rowptr[mid], end = rowptr[mid + 1];

    // read own mb row FIRST (partial write below clobbers it)
    unsigned int mv = *reinterpret_cast<const unsigned int*>(mb + (size_t)mid * 256 + 2 * l);

    float a0 = 0.f, a1 = 0.f, aw = 0.f;
    for (int base = beg; base < end; base += 8) {
        int ee[8], ss[8]; float ww[8];
#pragma unroll
        for (int u = 0; u < 8; ++u) {
            int idx = base + u;
            bool ok = idx < end;
            int ci = ok ? idx : end - 1;
            ee[u] = eid[ci]; ss[u] = src_csr[ci]; ww[u] = ok ? w_csr[ci] : 0.f;
        }
        unsigned int o[8]; unsigned short ev[8];
#pragma unroll
        for (int u = 0; u < 8; ++u) {
            o[u]  = *reinterpret_cast<const unsigned int*>(opb + (size_t)ss[u] * 128 + 2 * l);
            ev[u] = eab[(size_t)ee[u] * DEAT + l];
        }
#pragma unroll
        for (int u = 0; u < 8; ++u) {
            a0 += ww[u] * bflo(o[u]); a1 += ww[u] * bfhi(o[u]); aw += ww[u] * bf1(ev[u]);
        }
    }

    awb[(size_t)mid * 64 + l] = f2bf(aw);
    float ns = expf(s[mid] - Mx) * invS;
    float2 r = {ns * bflo(mv) + a0, ns * bfhi(mv) + a1};
    *reinterpret_cast<float2*>(out + (size_t)mid * 128 + 2 * l) = r;
}

// ---------------- MFMA epilogue: out = elu(partial + awb @ Wb), in-place on out -------
__launch_bounds__(256)
__global__ void k_epi(const unsigned short* __restrict__ awb,
                      const unsigned short* __restrict__ BtO2,   // [128][72] bf16 Wb^T
                      float* __restrict__ out)
{
    __shared__ unsigned short Bs[128 * 72];   // 18 KB, [col][k] stride 72
    const int t = threadIdx.x;
#pragma unroll
    for (int it = 0; it < 9; ++it) {
        int q = t + 256 * it;
        reinterpret_cast<uint4*>(Bs)[q] = reinterpret_cast<const uint4*>(BtO2)[q];
    }
    __syncthreads();

    const int w = t >> 6, l = t & 63, lr = l & 15, lk = l >> 4;
    const int row0 = blockIdx.x * 64 + w * 16;

    fx4 acc[8];
#pragma unroll
    for (int ni = 0; ni < 8; ++ni) acc[ni] = (fx4){0.f, 0.f, 0.f, 0.f};

#pragma unroll
    for (int k0 = 0; k0 < 64; k0 += 32) {
        int ar = row0 + lr; if (ar >= NMAT) ar = NMAT - 1;
        bfx8 af = *reinterpret_cast<const bfx8*>(awb + (size_t)ar * 64 + k0 + lk * 8);
#pragma unroll
        for (int ni = 0; ni < 8; ++ni) {
            bfx8 bf = *reinterpret_cast<const bfx8*>(&Bs[(ni * 16 + lr) * 72 + k0 + lk * 8]);
            acc[ni] = __builtin_amdgcn_mfma_f32_16x16x32_bf16(af, bf, acc[ni], 0, 0, 0);
        }
    }

    // C/D: col = ni*16 + (lane&15), row = (lane>>4)*4 + reg
#pragma unroll
    for (int ni = 0; ni < 8; ++ni)
#pragma unroll
        for (int r2 = 0; r2 < 4; ++r2) {
            int gr = row0 + lk * 4 + r2;
            if (gr < NMAT) {
                size_t idx = (size_t)gr * 128 + ni * 16 + lr;
                out[idx] = elu(out[idx] + acc[ni][r2]);
            }
        }
}

extern "C" void kernel_launch(void* const* d_in, const int* in_sizes, int n_in,
                              void* d_out, int out_size, void* d_ws, size_t ws_size,
                              hipStream_t stream)
{
    const float* materials  = (const float*)d_in[0];
    const float* operations = (const float*)d_in[1];
    const float* edge_attr  = (const float*)d_in[2];
    const int*   esrc       = (const int*)d_in[3];
    const int*   edst       = (const int*)d_in[4];
    const float* W_mat      = (const float*)d_in[5];
    const float* W_op       = (const float*)d_in[6];
    const float* att_self   = (const float*)d_in[7];
    const float* att_cross  = (const float*)d_in[8];
    float* out = (float*)d_out;

    // bf16 m lives inside d_out second row-halves: row mid at ushort offset mid*256 + 128
    unsigned short* mb = (unsigned short*)d_out + 128;

    char* p = (char*)d_ws;
    auto take = [&](size_t bytes) { char* r = p; p += (bytes + 255) & ~(size_t)255; return r; };

    unsigned short* opb     = (unsigned short*)take((size_t)NOPS * 128 * 2);   // 25.6 MB
    float*          s_buf   = (float*)take((size_t)(NMAT + NEDGE) * 4);        // 2.25 MB
    float*          dm      = (float*)take((size_t)NMAT * 4);
    float*          dop     = (float*)take((size_t)NOPS * 4);
    float*          asum    = (float*)take(128 * 4);
    float*          wv      = (float*)take(64 * 4);
    float*          wmc0    = (float*)take(128 * 4);
    float*          wmas    = (float*)take(128 * 4);
    float*          woc1    = (float*)take(DOPR * 4);
    unsigned short* BtM     = (unsigned short*)take(128 * 128 * 2);
    unsigned short* BtO     = (unsigned short*)take(128 * DOPR * 2);
    unsigned short* BtO2    = (unsigned short*)take(128 * 72 * 2);
    float*          part    = (float*)take(2048 * 4);
    float*          stats   = (float*)take(2 * 4);
    int*            cnt     = (int*)take((size_t)NMAT * 4);
    int*            loc     = (int*)take((size_t)NMAT * 4);
    int*            bsum    = (int*)take(256 * 4);
    int*            boff    = (int*)take(256 * 4);
    int*            rowptr  = (int*)take((size_t)(NMAT + 1) * 4);
    int*            cursor  = (int*)take((size_t)NMAT * 4);
    int*            eid     = (int*)take((size_t)NEDGE * 4);                   // 2.05 MB
    int*            src_csr = (int*)take((size_t)NEDGE * 4);                   // 2.05 MB
    float*          w_csr   = (float*)take((size_t)NEDGE * 4);                 // 2.05 MB
    unsigned short* eab     = (unsigned short*)take((size_t)NEDGE * DEAT * 2); // 65.5 MB
    unsigned short* awb     = (unsigned short*)take((size_t)NMAT * 64 * 2);    // 6.4 MB
    (void)ws_size;                                                             // ~108 MB total

    hipMemsetAsync(cnt, 0, NMAT * sizeof(int), stream);

    k_prepconv<<<97, 256, 0, stream>>>(att_self, att_cross, W_mat, W_op,
                                       asum, wv, wmc0, wmas, woc1, BtM, BtO, BtO2);
    gemm_mfma<128, 1><<<(NMAT + 127) / 128, 256, 0, stream>>>(
        materials, BtM, mb, 256, wmc0, wmas, dm, s_buf, NMAT);
    gemm_mfma<192, 2><<<(NOPS + 127) / 128, 256, 0, stream>>>(
        operations, BtO, opb, 128, woc1, nullptr, dop, nullptr, NOPS);
    k_edge_score<<<NEDGE / 128, 256, 0, stream>>>(edge_attr, esrc, edst, dm, dop, wv,
                                                  s_buf, cnt, eab);
    k_mid2<<<1024 + 196, 256, 0, stream>>>(s_buf, part, cnt, loc, bsum);
    k_fin<<<1, 256, 0, stream>>>(part, stats, bsum, boff);
    k_scanC<<<196, 256, 0, stream>>>(loc, boff, rowptr, cursor);
    k_fill<<<NEDGE / 256, 256, 0, stream>>>(esrc, edst, s_buf, stats, cursor,
                                            eid, src_csr, w_csr);
    k_agg<<<NMAT / 4, 256, 0, stream>>>(opb, mb, eab, eid, src_csr, w_csr,
                                        s_buf, stats, rowptr, awb, out);
    k_epi<<<(NMAT + 63) / 64, 256, 0, stream>>>(awb, BtO2, out);
}

// Round 8
// 211.209 us; speedup vs baseline: 2.0277x; 1.0151x over previous
//
#include <hip/hip_runtime.h>
#include <hip/hip_bf16.h>
#include <math.h>

#define NMAT  50000
#define NOPS  100000
#define NEDGE 512000
#define DOPR  192
#define DEAT  64

typedef __attribute__((ext_vector_type(8))) short bfx8;
typedef __attribute__((ext_vector_type(4))) float fx4;

static __device__ __forceinline__ float lrelu(float x) { return x > 0.f ? x : 0.2f * x; }
static __device__ __forceinline__ float elu(float x)   { return x > 0.f ? x : expm1f(x); }
static __device__ __forceinline__ unsigned short f2bf(float x) {
    unsigned int b = __float_as_uint(x);
    return (unsigned short)((b + 0x7fffu + ((b >> 16) & 1u)) >> 16);   // RNE
}
static __device__ __forceinline__ float bflo(unsigned int u) { return __uint_as_float(u << 16); }
static __device__ __forceinline__ float bfhi(unsigned int u) { return __uint_as_float(u & 0xffff0000u); }
static __device__ __forceinline__ float bf1(unsigned short u) { return __uint_as_float(((unsigned int)u) << 16); }

// ------- prep (block 0) + weight bf16-transpose conv (blocks 1..96) + cnt zeroing ------
__launch_bounds__(256)
__global__ void k_prepconv(const float* __restrict__ att_self, const float* __restrict__ att_cross,
                           const float* __restrict__ W_mat, const float* __restrict__ W_op,
                           float* __restrict__ asum, float* __restrict__ wv,
                           float* __restrict__ wmc0, float* __restrict__ wmas,
                           float* __restrict__ woc1,
                           unsigned short* __restrict__ BtM, unsigned short* __restrict__ BtO,
                           unsigned short* __restrict__ BtO2, int* __restrict__ cnt)
{
    const int b = blockIdx.x, t = threadIdx.x;
    for (int i = b * 256 + t; i < NMAT; i += 97 * 256) cnt[i] = 0;   // replaces memset
    if (b == 0) {
        __shared__ float as_sh[128];
        if (t < 128) { float v = att_self[t] + att_self[128 + t]; asum[t] = v; as_sh[t] = v; }
        __syncthreads();
        if (t < 128) {
            const float* wr = W_mat + (size_t)t * 128;
            float p0 = 0.f, p1 = 0.f;
            for (int j = 0; j < 128; ++j) { p0 += wr[j] * att_cross[j]; p1 += wr[j] * as_sh[j]; }
            wmc0[t] = p0; wmas[t] = p1;
        }
        const float* wr = W_op + (size_t)t * 128;
        float p = 0.f;
        for (int j = 0; j < 128; ++j) p += wr[j] * att_cross[128 + j];
        if (t < DOPR) woc1[t] = p; else wv[t - DOPR] = p;
    } else {
        int id = (b - 1) * 256 + t;
        if (id < 128 * 128) {
            int c = id >> 7, k = id & 127;
            BtM[c * 128 + k] = f2bf(W_mat[(size_t)k * 128 + c]);
        }
        if (id < 128 * DOPR) {
            int c = id / DOPR, k = id % DOPR;
            BtO[c * DOPR + k] = f2bf(W_op[(size_t)k * 128 + c]);
        }
        if (id < 128 * 64) {       // Wb^T for k_epi: BtO2[c][k2] = W_op[192+k2][c], stride 72
            int c = id >> 6, k = id & 63;
            BtO2[c * 72 + k] = f2bf(W_op[(size_t)(DOPR + k) * 128 + c]);
        }
    }
}

// ---------------- MFMA GEMM: Cb[M][cstride] = bf16(A[M][K] @ B), fused fp32 row-dots ----
// MODE 1: d1 = A.v1 (dm), d2 = lrelu(A.v2) (s_self).  MODE 2: d1 = A.v1 (dop).
template<int K, int MODE>
__launch_bounds__(256)
__global__ void gemm_mfma(const float* __restrict__ A, const unsigned short* __restrict__ Bt,
                          unsigned short* __restrict__ Cb, int cstride,
                          const float* __restrict__ v1, const float* __restrict__ v2,
                          float* __restrict__ d1, float* __restrict__ d2, int M)
{
    __shared__ unsigned short As[128 * 40];   // [row][k], stride 40
    __shared__ unsigned short Bs[128 * 40];   // [col][k]
    const int t = threadIdx.x;
    const int w = t >> 6, l = t & 63;
    const int lr = l & 15, lk = l >> 4;
    const int row0 = blockIdx.x * 128;

    fx4 acc[2][8];
#pragma unroll
    for (int i = 0; i < 2; ++i)
#pragma unroll
        for (int j = 0; j < 8; ++j) acc[i][j] = (fx4){0.f, 0.f, 0.f, 0.f};
    float pd1[4] = {0.f, 0.f, 0.f, 0.f};
    float pd2[4] = {0.f, 0.f, 0.f, 0.f};

    for (int k0 = 0; k0 < K; k0 += 32) {
#pragma unroll
        for (int it = 0; it < 4; ++it) {             // stage A (fp32 -> bf16) + dot partials
            int q  = t + 256 * it;
            int r  = q >> 3;
            int kk = (q & 7) * 4;
            int gr = row0 + r; if (gr >= M) gr = M - 1;
            float4 v = *reinterpret_cast<const float4*>(A + (size_t)gr * K + k0 + kk);
            ushort4 bb = {f2bf(v.x), f2bf(v.y), f2bf(v.z), f2bf(v.w)};
            *reinterpret_cast<ushort4*>(&As[r * 40 + kk]) = bb;
            pd1[it] += v.x * v1[k0 + kk] + v.y * v1[k0 + kk + 1]
                     + v.z * v1[k0 + kk + 2] + v.w * v1[k0 + kk + 3];
            if (MODE == 1)
                pd2[it] += v.x * v2[k0 + kk] + v.y * v2[k0 + kk + 1]
                         + v.z * v2[k0 + kk + 2] + v.w * v2[k0 + kk + 3];
        }
#pragma unroll
        for (int it = 0; it < 2; ++it) {             // stage B chunk (bf16, pre-transposed)
            int q  = t + 256 * it;
            int c  = q >> 2;
            int kg = (q & 3) * 8;
            uint4 vb = *reinterpret_cast<const uint4*>(&Bt[(size_t)c * K + k0 + kg]);
            *reinterpret_cast<uint4*>(&Bs[c * 40 + kg]) = vb;
        }
        __syncthreads();
        bfx8 af0 = *reinterpret_cast<const bfx8*>(&As[(w * 32 + lr) * 40 + lk * 8]);
        bfx8 af1 = *reinterpret_cast<const bfx8*>(&As[(w * 32 + 16 + lr) * 40 + lk * 8]);
#pragma unroll
        for (int ni = 0; ni < 8; ++ni) {
            bfx8 bf = *reinterpret_cast<const bfx8*>(&Bs[(ni * 16 + lr) * 40 + lk * 8]);
            acc[0][ni] = __builtin_amdgcn_mfma_f32_16x16x32_bf16(af0, bf, acc[0][ni], 0, 0, 0);
            acc[1][ni] = __builtin_amdgcn_mfma_f32_16x16x32_bf16(af1, bf, acc[1][ni], 0, 0, 0);
        }
        __syncthreads();
    }

    // C/D layout: col = lane&15, row = (lane>>4)*4 + reg
#pragma unroll
    for (int mi = 0; mi < 2; ++mi)
#pragma unroll
        for (int ni = 0; ni < 8; ++ni)
#pragma unroll
            for (int r2 = 0; r2 < 4; ++r2) {
                int row = row0 + w * 32 + mi * 16 + lk * 4 + r2;
                int col = ni * 16 + lr;
                if (row < M) Cb[(size_t)row * cstride + col] = f2bf(acc[mi][ni][r2]);
            }

    // fused row dots: 8 consecutive threads share one tile row
#pragma unroll
    for (int it = 0; it < 4; ++it) {
        float p1 = pd1[it], p2 = pd2[it];
#pragma unroll
        for (int off = 1; off < 8; off <<= 1) {
            p1 += __shfl_xor(p1, off, 8);
            if (MODE == 1) p2 += __shfl_xor(p2, off, 8);
        }
        int r  = (t + 256 * it) >> 3;
        int gr = row0 + r;
        if ((t & 7) == 0 && gr < M) {
            d1[gr] = p1;
            if (MODE == 1) d2[gr] = lrelu(p2);
        }
    }
}

// ---------------- edge scores + dst histogram + bf16 edge_attr copy ----------------
__launch_bounds__(256)
__global__ void k_edge_score(const float* __restrict__ edge_attr,
                             const int* __restrict__ esrc, const int* __restrict__ edst,
                             const float* __restrict__ dm, const float* __restrict__ dop,
                             const float* __restrict__ wv, float* __restrict__ s,
                             int* __restrict__ cnt, unsigned short* __restrict__ eab)
{
    int t = threadIdx.x;
    int g = t >> 4, q = t & 15;
    float4 wvq = *reinterpret_cast<const float4*>(wv + q * 4);
#pragma unroll
    for (int u = 0; u < 8; ++u) {
        int e = blockIdx.x * 128 + u * 16 + g;
        float4 av = *reinterpret_cast<const float4*>(edge_attr + (size_t)e * DEAT + q * 4);
        ushort4 bb = {f2bf(av.x), f2bf(av.y), f2bf(av.z), f2bf(av.w)};
        *reinterpret_cast<ushort4*>(&eab[(size_t)e * DEAT + q * 4]) = bb;
        float p = av.x * wvq.x + av.y * wvq.y + av.z * wvq.z + av.w * wvq.w;
#pragma unroll
        for (int off = 1; off < 16; off <<= 1) p += __shfl_xor(p, off, 16);
        if (q == 0) {
            int d = edst[e];
            s[NMAT + e] = lrelu(p + dm[d] + dop[esrc[e]]);
            atomicAdd(&cnt[d], 1);
        }
    }
}

// ------- fused: softmax partials (blocks 0..1023) + block-local scans (1024..1219) ----
__launch_bounds__(256)
__global__ void k_mid2(const float* __restrict__ s, float* __restrict__ part,
                       const int* __restrict__ cnt, int* __restrict__ loc,
                       int* __restrict__ bsum)
{
    const int t = threadIdx.x;
    if (blockIdx.x < 1024) {
        const int n = NMAT + NEDGE;
        float mx = -INFINITY, sm = 0.f;
        for (int i = blockIdx.x * 256 + t; i < n; i += 1024 * 256) {
            float x = s[i];
            if (x > mx) { sm = sm * expf(mx - x) + 1.f; mx = x; }
            else        { sm += expf(x - mx); }
        }
#pragma unroll
        for (int off = 1; off < 64; off <<= 1) {
            float om = __shfl_xor(mx, off, 64);
            float os = __shfl_xor(sm, off, 64);
            float nm = fmaxf(mx, om);
            sm = sm * expf(mx - nm) + os * expf(om - nm);
            mx = nm;
        }
        __shared__ float wm[4], wsum[4];
        int lane = t & 63, wvi = t >> 6;
        if (lane == 0) { wm[wvi] = mx; wsum[wvi] = sm; }
        __syncthreads();
        if (t == 0) {
            float M = wm[0], S = wsum[0];
            for (int i = 1; i < 4; ++i) {
                float nm = fmaxf(M, wm[i]);
                S = S * expf(M - nm) + wsum[i] * expf(wm[i] - nm);
                M = nm;
            }
            part[2 * blockIdx.x]     = M;
            part[2 * blockIdx.x + 1] = S;
        }
    } else {
        // 256-element block scan of cnt
        const int b = blockIdx.x - 1024;                 // 0..195
        const int idx = b * 256 + t;
        int v = (idx < NMAT) ? cnt[idx] : 0;
        __shared__ int sd[256];
        sd[t] = v;
        __syncthreads();
#pragma unroll
        for (int off = 1; off < 256; off <<= 1) {
            int x = (t >= off) ? sd[t - off] : 0;
            __syncthreads();
            sd[t] += x;
            __syncthreads();
        }
        if (idx < NMAT) loc[idx] = sd[t] - v;            // local exclusive
        if (t == 255) bsum[b] = sd[t];
    }
}

// ---- scan C (blocks 0..195): rowptr/cursor = loc + prefix(bsum); block 196: stats ----
__launch_bounds__(256)
__global__ void k_scanC(const int* __restrict__ loc, const int* __restrict__ bsum,
                        int* __restrict__ rowptr, int* __restrict__ cursor,
                        const float* __restrict__ part, float* __restrict__ stats)
{
    const int b = blockIdx.x, t = threadIdx.x;
    if (b < 196) {
        __shared__ int sd[256];
        sd[t] = (t < b) ? bsum[t] : 0;                   // t<b implies t<196
        __syncthreads();
#pragma unroll
        for (int off = 128; off > 0; off >>= 1) {
            if (t < off) sd[t] += sd[t + off];
            __syncthreads();
        }
        int boffb = sd[0];
        int idx = b * 256 + t;
        if (idx < NMAT) {
            int r = loc[idx] + boffb;
            rowptr[idx] = r;
            cursor[idx] = r;
        }
        if (idx == 0) rowptr[NMAT] = NEDGE;
    } else {
        float mx = -INFINITY, sm = 0.f;
        for (int i = t; i < 1024; i += 256) {
            float M = part[2 * i], S = part[2 * i + 1];
            float nm = fmaxf(mx, M);
            sm = sm * expf(mx - nm) + S * expf(M - nm);
            mx = nm;
        }
#pragma unroll
        for (int off = 1; off < 64; off <<= 1) {
            float om = __shfl_xor(mx, off, 64);
            float os = __shfl_xor(sm, off, 64);
            float nm = fmaxf(mx, om);
            sm = sm * expf(mx - nm) + os * expf(om - nm);
            mx = nm;
        }
        __shared__ float wm[4], wsum[4];
        int lane = t & 63, wv = t >> 6;
        if (lane == 0) { wm[wv] = mx; wsum[wv] = sm; }
        __syncthreads();
        if (t == 0) {
            float M = wm[0], S = wsum[0];
            for (int i = 1; i < 4; ++i) {
                float nm = fmaxf(M, wm[i]);
                S = S * expf(M - nm) + wsum[i] * expf(wm[i] - nm);
                M = nm;
            }
            stats[0] = M;
            stats[1] = 1.f / S;
        }
    }
}

// ---------------- fused CSR fill: one packed uint4 {eid, src, w, 0} per edge ----------
__launch_bounds__(256)
__global__ void k_fill(const int* __restrict__ esrc, const int* __restrict__ edst,
                       const float* __restrict__ s, const float* __restrict__ stats,
                       int* __restrict__ cursor, uint4* __restrict__ csr)
{
    int e = blockIdx.x * 256 + threadIdx.x;
    if (e >= NEDGE) return;
    float wg = expf(s[NMAT + e] - stats[0]) * stats[1];
    int pos = atomicAdd(&cursor[edst[e]], 1);
    csr[pos] = make_uint4((unsigned)e, (unsigned)esrc[e], __float_as_uint(wg), 0u);
}

// ---------------- CSR aggregate (masked 16-wide, no LDS) ----------------
// wave per material: a = sum w*opb[src], aw = sum w*eab[e]
// writes awb[mid][64] bf16 and partial = ns*m + ap into out (fp32, finished by k_epi)
__launch_bounds__(256)
__global__ void k_agg(const unsigned short* __restrict__ opb,
                      const unsigned short* mb,            // NO restrict: aliases out
                      const unsigned short* __restrict__ eab,
                      const uint4* __restrict__ csr,
                      const float* __restrict__ s, const float* __restrict__ stats,
                      const int* __restrict__ rowptr,
                      unsigned short* __restrict__ awb, float* out)   // out aliases mb
{
    const int t = threadIdx.x;
    const int w = t >> 6, l = t & 63;
    const int mid = blockIdx.x * 4 + w;
    const float Mx = stats[0], invS = stats[1];
    const int beg = rowptr[mid], end = rowptr[mid + 1];

    // read own mb row FIRST (partial write below clobbers it)
    unsigned int mv = *reinterpret_cast<const unsigned int*>(mb + (size_t)mid * 256 + 2 * l);

    float a0 = 0.f, a1 = 0.f, aw = 0.f;
    for (int base = beg; base < end; base += 16) {
        unsigned int ee[16], ss[16]; float ww[16];
#pragma unroll
        for (int u = 0; u < 16; ++u) {
            int idx = base + u;
            bool ok = idx < end;
            uint4 mt = csr[ok ? idx : end - 1];
            ee[u] = mt.x; ss[u] = mt.y; ww[u] = ok ? __uint_as_float(mt.z) : 0.f;
        }
        unsigned int o[16]; unsigned short ev[16];
#pragma unroll
        for (int u = 0; u < 16; ++u) {
            o[u]  = *reinterpret_cast<const unsigned int*>(opb + (size_t)ss[u] * 128 + 2 * l);
            ev[u] = eab[(size_t)ee[u] * DEAT + l];
        }
#pragma unroll
        for (int u = 0; u < 16; ++u) {
            a0 += ww[u] * bflo(o[u]); a1 += ww[u] * bfhi(o[u]); aw += ww[u] * bf1(ev[u]);
        }
    }

    awb[(size_t)mid * 64 + l] = f2bf(aw);
    float ns = expf(s[mid] - Mx) * invS;
    float2 r = {ns * bflo(mv) + a0, ns * bfhi(mv) + a1};
    *reinterpret_cast<float2*>(out + (size_t)mid * 128 + 2 * l) = r;
}

// ---------------- MFMA epilogue: out = elu(partial + awb @ Wb), in-place on out -------
__launch_bounds__(256)
__global__ void k_epi(const unsigned short* __restrict__ awb,
                      const unsigned short* __restrict__ BtO2,   // [128][72] bf16 Wb^T
                      float* __restrict__ out)
{
    __shared__ unsigned short Bs[128 * 72];   // 18 KB, [col][k] stride 72
    const int t = threadIdx.x;
#pragma unroll
    for (int it = 0; it < 9; ++it) {
        int q = t + 256 * it;
        reinterpret_cast<uint4*>(Bs)[q] = reinterpret_cast<const uint4*>(BtO2)[q];
    }
    __syncthreads();

    const int w = t >> 6, l = t & 63, lr = l & 15, lk = l >> 4;
    const int row0 = blockIdx.x * 64 + w * 16;

    fx4 acc[8];
#pragma unroll
    for (int ni = 0; ni < 8; ++ni) acc[ni] = (fx4){0.f, 0.f, 0.f, 0.f};

#pragma unroll
    for (int k0 = 0; k0 < 64; k0 += 32) {
        int ar = row0 + lr; if (ar >= NMAT) ar = NMAT - 1;
        bfx8 af = *reinterpret_cast<const bfx8*>(awb + (size_t)ar * 64 + k0 + lk * 8);
#pragma unroll
        for (int ni = 0; ni < 8; ++ni) {
            bfx8 bf = *reinterpret_cast<const bfx8*>(&Bs[(ni * 16 + lr) * 72 + k0 + lk * 8]);
            acc[ni] = __builtin_amdgcn_mfma_f32_16x16x32_bf16(af, bf, acc[ni], 0, 0, 0);
        }
    }

    // C/D: col = ni*16 + (lane&15), row = (lane>>4)*4 + reg
#pragma unroll
    for (int ni = 0; ni < 8; ++ni)
#pragma unroll
        for (int r2 = 0; r2 < 4; ++r2) {
            int gr = row0 + lk * 4 + r2;
            if (gr < NMAT) {
                size_t idx = (size_t)gr * 128 + ni * 16 + lr;
                out[idx] = elu(out[idx] + acc[ni][r2]);
            }
        }
}

extern "C" void kernel_launch(void* const* d_in, const int* in_sizes, int n_in,
                              void* d_out, int out_size, void* d_ws, size_t ws_size,
                              hipStream_t stream)
{
    const float* materials  = (const float*)d_in[0];
    const float* operations = (const float*)d_in[1];
    const float* edge_attr  = (const float*)d_in[2];
    const int*   esrc       = (const int*)d_in[3];
    const int*   edst       = (const int*)d_in[4];
    const float* W_mat      = (const float*)d_in[5];
    const float* W_op       = (const float*)d_in[6];
    const float* att_self   = (const float*)d_in[7];
    const float* att_cross  = (const float*)d_in[8];
    float* out = (float*)d_out;

    // bf16 m lives inside d_out second row-halves: row mid at ushort offset mid*256 + 128
    unsigned short* mb = (unsigned short*)d_out + 128;

    char* p = (char*)d_ws;
    auto take = [&](size_t bytes) { char* r = p; p += (bytes + 255) & ~(size_t)255; return r; };

    unsigned short* opb     = (unsigned short*)take((size_t)NOPS * 128 * 2);   // 25.6 MB
    float*          s_buf   = (float*)take((size_t)(NMAT + NEDGE) * 4);        // 2.25 MB
    float*          dm      = (float*)take((size_t)NMAT * 4);
    float*          dop     = (float*)take((size_t)NOPS * 4);
    float*          asum    = (float*)take(128 * 4);
    float*          wv      = (float*)take(64 * 4);
    float*          wmc0    = (float*)take(128 * 4);
    float*          wmas    = (float*)take(128 * 4);
    float*          woc1    = (float*)take(DOPR * 4);
    unsigned short* BtM     = (unsigned short*)take(128 * 128 * 2);
    unsigned short* BtO     = (unsigned short*)take(128 * DOPR * 2);
    unsigned short* BtO2    = (unsigned short*)take(128 * 72 * 2);
    float*          part    = (float*)take(2048 * 4);
    float*          stats   = (float*)take(2 * 4);
    int*            cnt     = (int*)take((size_t)NMAT * 4);
    int*            loc     = (int*)take((size_t)NMAT * 4);
    int*            bsum    = (int*)take(256 * 4);
    int*            rowptr  = (int*)take((size_t)(NMAT + 1) * 4);
    int*            cursor  = (int*)take((size_t)NMAT * 4);
    uint4*          csr     = (uint4*)take((size_t)NEDGE * 16);                // 8.2 MB
    unsigned short* eab     = (unsigned short*)take((size_t)NEDGE * DEAT * 2); // 65.5 MB
    unsigned short* awb     = (unsigned short*)take((size_t)NMAT * 64 * 2);    // 6.4 MB
    (void)ws_size;                                                             // ~110 MB total

    k_prepconv<<<97, 256, 0, stream>>>(att_self, att_cross, W_mat, W_op,
                                       asum, wv, wmc0, wmas, woc1, BtM, BtO, BtO2, cnt);
    gemm_mfma<128, 1><<<(NMAT + 127) / 128, 256, 0, stream>>>(
        materials, BtM, mb, 256, wmc0, wmas, dm, s_buf, NMAT);
    gemm_mfma<192, 2><<<(NOPS + 127) / 128, 256, 0, stream>>>(
        operations, BtO, opb, 128, woc1, nullptr, dop, nullptr, NOPS);
    k_edge_score<<<NEDGE / 128, 256, 0, stream>>>(edge_attr, esrc, edst, dm, dop, wv,
                                                  s_buf, cnt, eab);
    k_mid2<<<1024 + 196, 256, 0, stream>>>(s_buf, part, cnt, loc, bsum);
    k_scanC<<<197, 256, 0, stream>>>(loc, bsum, rowptr, cursor, part, stats);
    k_fill<<<NEDGE / 256, 256, 0, stream>>>(esrc, edst, s_buf, stats, cursor, csr);
    k_agg<<<NMAT / 4, 256, 0, stream>>>(opb, mb, eab, csr, s_buf, stats, rowptr, awb, out);
    k_epi<<<(NMAT + 63) / 64, 256, 0, stream>>>(awb, BtO2, out);
}

// Round 10
// 195.652 us; speedup vs baseline: 2.1889x; 1.0795x over previous
//
#include <hip/hip_runtime.h>
#include <hip/hip_bf16.h>
#include <math.h>

#define NMAT  50000
#define NOPS  100000
#define NEDGE 512000
#define DOPR  192
#define DEAT  64

typedef __attribute__((ext_vector_type(8))) short bfx8;
typedef __attribute__((ext_vector_type(4))) float fx4;

static __device__ __forceinline__ float lrelu(float x) { return x > 0.f ? x : 0.2f * x; }
static __device__ __forceinline__ float elu(float x)   { return x > 0.f ? x : expm1f(x); }
static __device__ __forceinline__ unsigned short f2bf(float x) {
    unsigned int b = __float_as_uint(x);
    return (unsigned short)((b + 0x7fffu + ((b >> 16) & 1u)) >> 16);   // RNE
}
static __device__ __forceinline__ float bflo(unsigned int u) { return __uint_as_float(u << 16); }
static __device__ __forceinline__ float bfhi(unsigned int u) { return __uint_as_float(u & 0xffff0000u); }
static __device__ __forceinline__ float bf1(unsigned short u) { return __uint_as_float(((unsigned int)u) << 16); }

// ------- prep (block 0) + weight bf16-transpose conv (blocks 1..96) + cnt zeroing ------
__launch_bounds__(256)
__global__ void k_prepconv(const float* __restrict__ att_self, const float* __restrict__ att_cross,
                           const float* __restrict__ W_mat, const float* __restrict__ W_op,
                           float* __restrict__ asum, float* __restrict__ wv,
                           float* __restrict__ wmc0, float* __restrict__ wmas,
                           float* __restrict__ woc1,
                           unsigned short* __restrict__ BtM, unsigned short* __restrict__ BtO,
                           unsigned short* __restrict__ BtO2, int* __restrict__ cnt)
{
    const int b = blockIdx.x, t = threadIdx.x;
    for (int i = b * 256 + t; i < NMAT; i += 97 * 256) cnt[i] = 0;   // replaces memset
    if (b == 0) {
        __shared__ float as_sh[128];
        if (t < 128) { float v = att_self[t] + att_self[128 + t]; asum[t] = v; as_sh[t] = v; }
        __syncthreads();
        if (t < 128) {
            const float* wr = W_mat + (size_t)t * 128;
            float p0 = 0.f, p1 = 0.f;
            for (int j = 0; j < 128; ++j) { p0 += wr[j] * att_cross[j]; p1 += wr[j] * as_sh[j]; }
            wmc0[t] = p0; wmas[t] = p1;
        }
        const float* wr = W_op + (size_t)t * 128;
        float p = 0.f;
        for (int j = 0; j < 128; ++j) p += wr[j] * att_cross[128 + j];
        if (t < DOPR) woc1[t] = p; else wv[t - DOPR] = p;
    } else {
        int id = (b - 1) * 256 + t;
        if (id < 128 * 128) {
            int c = id >> 7, k = id & 127;
            BtM[c * 128 + k] = f2bf(W_mat[(size_t)k * 128 + c]);
        }
        if (id < 128 * DOPR) {
            int c = id / DOPR, k = id % DOPR;
            BtO[c * DOPR + k] = f2bf(W_op[(size_t)k * 128 + c]);
        }
        if (id < 128 * 64) {       // Wb^T for k_epi: BtO2[c][k2] = W_op[192+k2][c], stride 72
            int c = id >> 6, k = id & 63;
            BtO2[c * 72 + k] = f2bf(W_op[(size_t)(DOPR + k) * 128 + c]);
        }
    }
}

// ---------------- MFMA GEMM body: Cb[M][cstride] = bf16(A[M][K] @ B), fused row-dots ----
// MODE 1: d1 = A.v1 (dm), d2 = lrelu(A.v2) (s_self).  MODE 2: d1 = A.v1 (dop).
// A-tile loads are NONTEMPORAL (stream-once; keep LLC for opb/eab).
template<int K, int MODE>
static __device__ __forceinline__ void gemm_body(
    int bid, unsigned short* As, unsigned short* Bs,
    const float* __restrict__ A, const unsigned short* __restrict__ Bt,
    unsigned short* __restrict__ Cb, int cstride,
    const float* __restrict__ v1, const float* __restrict__ v2,
    float* __restrict__ d1, float* __restrict__ d2, int M)
{
    const int t = threadIdx.x;
    const int w = t >> 6, l = t & 63;
    const int lr = l & 15, lk = l >> 4;
    const int row0 = bid * 128;

    fx4 acc[2][8];
#pragma unroll
    for (int i = 0; i < 2; ++i)
#pragma unroll
        for (int j = 0; j < 8; ++j) acc[i][j] = (fx4){0.f, 0.f, 0.f, 0.f};
    float pd1[4] = {0.f, 0.f, 0.f, 0.f};
    float pd2[4] = {0.f, 0.f, 0.f, 0.f};

    for (int k0 = 0; k0 < K; k0 += 32) {
#pragma unroll
        for (int it = 0; it < 4; ++it) {             // stage A (fp32 -> bf16) + dot partials
            int q  = t + 256 * it;
            int r  = q >> 3;
            int kk = (q & 7) * 4;
            int gr = row0 + r; if (gr >= M) gr = M - 1;
            fx4 v = __builtin_nontemporal_load(
                reinterpret_cast<const fx4*>(A + (size_t)gr * K + k0 + kk));
            ushort4 bb = {f2bf(v[0]), f2bf(v[1]), f2bf(v[2]), f2bf(v[3])};
            *reinterpret_cast<ushort4*>(&As[r * 40 + kk]) = bb;
            pd1[it] += v[0] * v1[k0 + kk] + v[1] * v1[k0 + kk + 1]
                     + v[2] * v1[k0 + kk + 2] + v[3] * v1[k0 + kk + 3];
            if (MODE == 1)
                pd2[it] += v[0] * v2[k0 + kk] + v[1] * v2[k0 + kk + 1]
                         + v[2] * v2[k0 + kk + 2] + v[3] * v2[k0 + kk + 3];
        }
#pragma unroll
        for (int it = 0; it < 2; ++it) {             // stage B chunk (bf16, pre-transposed)
            int q  = t + 256 * it;
            int c  = q >> 2;
            int kg = (q & 3) * 8;
            uint4 vb = *reinterpret_cast<const uint4*>(&Bt[(size_t)c * K + k0 + kg]);
            *reinterpret_cast<uint4*>(&Bs[c * 40 + kg]) = vb;
        }
        __syncthreads();
        bfx8 af0 = *reinterpret_cast<const bfx8*>(&As[(w * 32 + lr) * 40 + lk * 8]);
        bfx8 af1 = *reinterpret_cast<const bfx8*>(&As[(w * 32 + 16 + lr) * 40 + lk * 8]);
#pragma unroll
        for (int ni = 0; ni < 8; ++ni) {
            bfx8 bf = *reinterpret_cast<const bfx8*>(&Bs[(ni * 16 + lr) * 40 + lk * 8]);
            acc[0][ni] = __builtin_amdgcn_mfma_f32_16x16x32_bf16(af0, bf, acc[0][ni], 0, 0, 0);
            acc[1][ni] = __builtin_amdgcn_mfma_f32_16x16x32_bf16(af1, bf, acc[1][ni], 0, 0, 0);
        }
        __syncthreads();
    }

    // C/D layout: col = lane&15, row = (lane>>4)*4 + reg
#pragma unroll
    for (int mi = 0; mi < 2; ++mi)
#pragma unroll
        for (int ni = 0; ni < 8; ++ni)
#pragma unroll
            for (int r2 = 0; r2 < 4; ++r2) {
                int row = row0 + w * 32 + mi * 16 + lk * 4 + r2;
                int col = ni * 16 + lr;
                if (row < M) Cb[(size_t)row * cstride + col] = f2bf(acc[mi][ni][r2]);
            }

    // fused row dots: 8 consecutive threads share one tile row
#pragma unroll
    for (int it = 0; it < 4; ++it) {
        float p1 = pd1[it], p2 = pd2[it];
#pragma unroll
        for (int off = 1; off < 8; off <<= 1) {
            p1 += __shfl_xor(p1, off, 8);
            if (MODE == 1) p2 += __shfl_xor(p2, off, 8);
        }
        int r  = (t + 256 * it) >> 3;
        int gr = row0 + r;
        if ((t & 7) == 0 && gr < M) {
            d1[gr] = p1;
            if (MODE == 1) d2[gr] = lrelu(p2);
        }
    }
}

// ---------------- both GEMMs in one dispatch: blocks [0,391) mat, [391,1173) ops -------
#define GBLK_M ((NMAT + 127) / 128)     // 391
#define GBLK_O ((NOPS + 127) / 128)     // 782
__launch_bounds__(256)
__global__ void k_gemms(const float* __restrict__ materials, const unsigned short* __restrict__ BtM,
                        unsigned short* __restrict__ mb,
                        const float* __restrict__ wmc0, const float* __restrict__ wmas,
                        float* __restrict__ dm, float* __restrict__ s_buf,
                        const float* __restrict__ operations, const unsigned short* __restrict__ BtO,
                        unsigned short* __restrict__ opb,
                        const float* __restrict__ woc1, float* __restrict__ dop)
{
    __shared__ unsigned short As[128 * 40];
    __shared__ unsigned short Bs[128 * 40];
    if (blockIdx.x < GBLK_M)
        gemm_body<128, 1>(blockIdx.x, As, Bs, materials, BtM, mb, 256,
                          wmc0, wmas, dm, s_buf, NMAT);
    else
        gemm_body<192, 2>(blockIdx.x - GBLK_M, As, Bs, operations, BtO, opb, 128,
                          woc1, nullptr, dop, nullptr, NOPS);
}

// ---------------- edge scores + dst histogram + bf16 edge_attr copy ----------------
// edge_attr read is NONTEMPORAL (stream-once); eab write stays cached (reused by k_agg).
__launch_bounds__(256)
__global__ void k_edge_score(const float* __restrict__ edge_attr,
                             const int* __restrict__ esrc, const int* __restrict__ edst,
                             const float* __restrict__ dm, const float* __restrict__ dop,
                             const float* __restrict__ wv, float* __restrict__ s,
                             int* __restrict__ cnt, unsigned short* __restrict__ eab)
{
    int t = threadIdx.x;
    int g = t >> 4, q = t & 15;
    float4 wvq = *reinterpret_cast<const float4*>(wv + q * 4);
#pragma unroll
    for (int u = 0; u < 8; ++u) {
        int e = blockIdx.x * 128 + u * 16 + g;
        fx4 av = __builtin_nontemporal_load(
            reinterpret_cast<const fx4*>(edge_attr + (size_t)e * DEAT + q * 4));
        ushort4 bb = {f2bf(av[0]), f2bf(av[1]), f2bf(av[2]), f2bf(av[3])};
        *reinterpret_cast<ushort4*>(&eab[(size_t)e * DEAT + q * 4]) = bb;
        float p = av[0] * wvq.x + av[1] * wvq.y + av[2] * wvq.z + av[3] * wvq.w;
#pragma unroll
        for (int off = 1; off < 16; off <<= 1) p += __shfl_xor(p, off, 16);
        if (q == 0) {
            int d = edst[e];
            s[NMAT + e] = lrelu(p + dm[d] + dop[esrc[e]]);
            atomicAdd(&cnt[d], 1);
        }
    }
}

// ------- fused: softmax partials (blocks 0..1023) + block-local scans (1024..1219) ----
__launch_bounds__(256)
__global__ void k_mid2(const float* __restrict__ s, float* __restrict__ part,
                       const int* __restrict__ cnt, int* __restrict__ loc,
                       int* __restrict__ bsum)
{
    const int t = threadIdx.x;
    if (blockIdx.x < 1024) {
        const int n = NMAT + NEDGE;
        float mx = -INFINITY, sm = 0.f;
        for (int i = blockIdx.x * 256 + t; i < n; i += 1024 * 256) {
            float x = s[i];
            if (x > mx) { sm = sm * expf(mx - x) + 1.f; mx = x; }
            else        { sm += expf(x - mx); }
        }
#pragma unroll
        for (int off = 1; off < 64; off <<= 1) {
            float om = __shfl_xor(mx, off, 64);
            float os = __shfl_xor(sm, off, 64);
            float nm = fmaxf(mx, om);
            sm = sm * expf(mx - nm) + os * expf(om - nm);
            mx = nm;
        }
        __shared__ float wm[4], wsum[4];
        int lane = t & 63, wvi = t >> 6;
        if (lane == 0) { wm[wvi] = mx; wsum[wvi] = sm; }
        __syncthreads();
        if (t == 0) {
            float M = wm[0], S = wsum[0];
            for (int i = 1; i < 4; ++i) {
                float nm = fmaxf(M, wm[i]);
                S = S * expf(M - nm) + wsum[i] * expf(wm[i] - nm);
                M = nm;
            }
            part[2 * blockIdx.x]     = M;
            part[2 * blockIdx.x + 1] = S;
        }
    } else {
        // 256-element block scan of cnt
        const int b = blockIdx.x - 1024;                 // 0..195
        const int idx = b * 256 + t;
        int v = (idx < NMAT) ? cnt[idx] : 0;
        __shared__ int sd[256];
        sd[t] = v;
        __syncthreads();
#pragma unroll
        for (int off = 1; off < 256; off <<= 1) {
            int x = (t >= off) ? sd[t - off] : 0;
            __syncthreads();
            sd[t] += x;
            __syncthreads();
        }
        if (idx < NMAT) loc[idx] = sd[t] - v;            // local exclusive
        if (t == 255) bsum[b] = sd[t];
    }
}

// ---- scan C (blocks 0..195): rowptr/cursor = loc + prefix(bsum); block 196: stats ----
__launch_bounds__(256)
__global__ void k_scanC(const int* __restrict__ loc, const int* __restrict__ bsum,
                        int* __restrict__ rowptr, int* __restrict__ cursor,
                        const float* __restrict__ part, float* __restrict__ stats)
{
    const int b = blockIdx.x, t = threadIdx.x;
    if (b < 196) {
        __shared__ int sd[256];
        sd[t] = (t < b) ? bsum[t] : 0;                   // t<b implies t<196
        __syncthreads();
#pragma unroll
        for (int off = 128; off > 0; off >>= 1) {
            if (t < off) sd[t] += sd[t + off];
            __syncthreads();
        }
        int boffb = sd[0];
        int idx = b * 256 + t;
        if (idx < NMAT) {
            int r = loc[idx] + boffb;
            rowptr[idx] = r;
            cursor[idx] = r;
        }
        if (idx == 0) rowptr[NMAT] = NEDGE;
    } else {
        float mx = -INFINITY, sm = 0.f;
        for (int i = t; i < 1024; i += 256) {
            float M = part[2 * i], S = part[2 * i + 1];
            float nm = fmaxf(mx, M);
            sm = sm * expf(mx - nm) + S * expf(M - nm);
            mx = nm;
        }
#pragma unroll
        for (int off = 1; off < 64; off <<= 1) {
            float om = __shfl_xor(mx, off, 64);
            float os = __shfl_xor(sm, off, 64);
            float nm = fmaxf(mx, om);
            sm = sm * expf(mx - nm) + os * expf(om - nm);
            mx = nm;
        }
        __shared__ float wm[4], wsum[4];
        int lane = t & 63, wv = t >> 6;
        if (lane == 0) { wm[wv] = mx; wsum[wv] = sm; }
        __syncthreads();
        if (t == 0) {
            float M = wm[0], S = wsum[0];
            for (int i = 1; i < 4; ++i) {
                float nm = fmaxf(M, wm[i]);
                S = S * expf(M - nm) + wsum[i] * expf(wm[i] - nm);
                M = nm;
            }
            stats[0] = M;
            stats[1] = 1.f / S;
        }
    }
}

// ---------------- fused CSR fill: one packed uint4 {eid, src, w, 0} per edge ----------
__launch_bounds__(256)
__global__ void k_fill(const int* __restrict__ esrc, const int* __restrict__ edst,
                       const float* __restrict__ s, const float* __restrict__ stats,
                       int* __restrict__ cursor, uint4* __restrict__ csr)
{
    int e = blockIdx.x * 256 + threadIdx.x;
    if (e >= NEDGE) return;
    float wg = expf(s[NMAT + e] - stats[0]) * stats[1];
    int pos = atomicAdd(&cursor[edst[e]], 1);
    csr[pos] = make_uint4((unsigned)e, (unsigned)esrc[e], __float_as_uint(wg), 0u);
}

// ---------------- CSR aggregate (masked 16-wide, no LDS) ----------------
// wave per material: a = sum w*opb[src], aw = sum w*eab[e]
// writes awb[mid][64] bf16 and partial = ns*m + ap into out (fp32, finished by k_epi)
__launch_bounds__(256)
__global__ void k_agg(const unsigned short* __restrict__ opb,
                      const unsigned short* mb,            // NO restrict: aliases out
                      const unsigned short* __restrict__ eab,
                      const uint4* __restrict__ csr,
                      const float* __restrict__ s, const float* __restrict__ stats,
                      const int* __restrict__ rowptr,
                      unsigned short* __restrict__ awb, float* out)   // out aliases mb
{
    const int t = threadIdx.x;
    const int w = t >> 6, l = t & 63;
    const int mid = blockIdx.x * 4 + w;
    const float Mx = stats[0], invS = stats[1];
    const int beg = rowptr[mid], end = rowptr[mid + 1];

    // read own mb row FIRST (partial write below clobbers it)
    unsigned int mv = *reinterpret_cast<const unsigned int*>(mb + (size_t)mid * 256 + 2 * l);

    float a0 = 0.f, a1 = 0.f, aw = 0.f;
    for (int base = beg; base < end; base += 16) {
        unsigned int ee[16], ss[16]; float ww[16];
#pragma unroll
        for (int u = 0; u < 16; ++u) {
            int idx = base + u;
            bool ok = idx < end;
            uint4 mt = csr[ok ? idx : end - 1];
            ee[u] = mt.x; ss[u] = mt.y; ww[u] = ok ? __uint_as_float(mt.z) : 0.f;
        }
        unsigned int o[16]; unsigned short ev[16];
#pragma unroll
        for (int u = 0; u < 16; ++u) {
            o[u]  = *reinterpret_cast<const unsigned int*>(opb + (size_t)ss[u] * 128 + 2 * l);
            ev[u] = eab[(size_t)ee[u] * DEAT + l];
        }
#pragma unroll
        for (int u = 0; u < 16; ++u) {
            a0 += ww[u] * bflo(o[u]); a1 += ww[u] * bfhi(o[u]); aw += ww[u] * bf1(ev[u]);
        }
    }

    awb[(size_t)mid * 64 + l] = f2bf(aw);
    float ns = expf(s[mid] - Mx) * invS;
    float2 r = {ns * bflo(mv) + a0, ns * bfhi(mv) + a1};
    *reinterpret_cast<float2*>(out + (size_t)mid * 128 + 2 * l) = r;
}

// ---------------- MFMA epilogue: out = elu(partial + awb @ Wb), in-place on out -------
__launch_bounds__(256)
__global__ void k_epi(const unsigned short* __restrict__ awb,
                      const unsigned short* __restrict__ BtO2,   // [128][72] bf16 Wb^T
                      float* __restrict__ out)
{
    __shared__ unsigned short Bs[128 * 72];   // 18 KB, [col][k] stride 72
    const int t = threadIdx.x;
#pragma unroll
    for (int it = 0; it < 9; ++it) {
        int q = t + 256 * it;
        reinterpret_cast<uint4*>(Bs)[q] = reinterpret_cast<const uint4*>(BtO2)[q];
    }
    __syncthreads();

    const int w = t >> 6, l = t & 63, lr = l & 15, lk = l >> 4;
    const int row0 = blockIdx.x * 64 + w * 16;

    fx4 acc[8];
#pragma unroll
    for (int ni = 0; ni < 8; ++ni) acc[ni] = (fx4){0.f, 0.f, 0.f, 0.f};

#pragma unroll
    for (int k0 = 0; k0 < 64; k0 += 32) {
        int ar = row0 + lr; if (ar >= NMAT) ar = NMAT - 1;
        bfx8 af = *reinterpret_cast<const bfx8*>(awb + (size_t)ar * 64 + k0 + lk * 8);
#pragma unroll
        for (int ni = 0; ni < 8; ++ni) {
            bfx8 bf = *reinterpret_cast<const bfx8*>(&Bs[(ni * 16 + lr) * 72 + k0 + lk * 8]);
            acc[ni] = __builtin_amdgcn_mfma_f32_16x16x32_bf16(af, bf, acc[ni], 0, 0, 0);
        }
    }

    // C/D: col = ni*16 + (lane&15), row = (lane>>4)*4 + reg
#pragma unroll
    for (int ni = 0; ni < 8; ++ni)
#pragma unroll
        for (int r2 = 0; r2 < 4; ++r2) {
            int gr = row0 + lk * 4 + r2;
            if (gr < NMAT) {
                size_t idx = (size_t)gr * 128 + ni * 16 + lr;
                out[idx] = elu(out[idx] + acc[ni][r2]);
            }
        }
}

extern "C" void kernel_launch(void* const* d_in, const int* in_sizes, int n_in,
                              void* d_out, int out_size, void* d_ws, size_t ws_size,
                              hipStream_t stream)
{
    const float* materials  = (const float*)d_in[0];
    const float* operations = (const float*)d_in[1];
    const float* edge_attr  = (const float*)d_in[2];
    const int*   esrc       = (const int*)d_in[3];
    const int*   edst       = (const int*)d_in[4];
    const float* W_mat      = (const float*)d_in[5];
    const float* W_op       = (const float*)d_in[6];
    const float* att_self   = (const float*)d_in[7];
    const float* att_cross  = (const float*)d_in[8];
    float* out = (float*)d_out;

    // bf16 m lives inside d_out second row-halves: row mid at ushort offset mid*256 + 128
    unsigned short* mb = (unsigned short*)d_out + 128;

    char* p = (char*)d_ws;
    auto take = [&](size_t bytes) { char* r = p; p += (bytes + 255) & ~(size_t)255; return r; };

    unsigned short* opb     = (unsigned short*)take((size_t)NOPS * 128 * 2);   // 25.6 MB
    float*          s_buf   = (float*)take((size_t)(NMAT + NEDGE) * 4);        // 2.25 MB
    float*          dm      = (float*)take((size_t)NMAT * 4);
    float*          dop     = (float*)take((size_t)NOPS * 4);
    float*          asum    = (float*)take(128 * 4);
    float*          wv      = (float*)take(64 * 4);
    float*          wmc0    = (float*)take(128 * 4);
    float*          wmas    = (float*)take(128 * 4);
    float*          woc1    = (float*)take(DOPR * 4);
    unsigned short* BtM     = (unsigned short*)take(128 * 128 * 2);
    unsigned short* BtO     = (unsigned short*)take(128 * DOPR * 2);
    unsigned short* BtO2    = (unsigned short*)take(128 * 72 * 2);
    float*          part    = (float*)take(2048 * 4);
    float*          stats   = (float*)take(2 * 4);
    int*            cnt     = (int*)take((size_t)NMAT * 4);
    int*            loc     = (int*)take((size_t)NMAT * 4);
    int*            bsum    = (int*)take(256 * 4);
    int*            rowptr  = (int*)take((size_t)(NMAT + 1) * 4);
    int*            cursor  = (int*)take((size_t)NMAT * 4);
    uint4*          csr     = (uint4*)take((size_t)NEDGE * 16);                // 8.2 MB
    unsigned short* eab     = (unsigned short*)take((size_t)NEDGE * DEAT * 2); // 65.5 MB
    unsigned short* awb     = (unsigned short*)take((size_t)NMAT * 64 * 2);    // 6.4 MB
    (void)ws_size;                                                             // ~110 MB total

    k_prepconv<<<97, 256, 0, stream>>>(att_self, att_cross, W_mat, W_op,
                                       asum, wv, wmc0, wmas, woc1, BtM, BtO, BtO2, cnt);
    k_gemms<<<GBLK_M + GBLK_O, 256, 0, stream>>>(materials, BtM, mb, wmc0, wmas, dm, s_buf,
                                                 operations, BtO, opb, woc1, dop);
    k_edge_score<<<NEDGE / 128, 256, 0, stream>>>(edge_attr, esrc, edst, dm, dop, wv,
                                                  s_buf, cnt, eab);
    k_mid2<<<1024 + 196, 256, 0, stream>>>(s_buf, part, cnt, loc, bsum);
    k_scanC<<<197, 256, 0, stream>>>(loc, bsum, rowptr, cursor, part, stats);
    k_fill<<<NEDGE / 256, 256, 0, stream>>>(esrc, edst, s_buf, stats, cursor, csr);
    k_agg<<<NMAT / 4, 256, 0, stream>>>(opb, mb, eab, csr, s_buf, stats, rowptr, awb, out);
    k_epi<<<(NMAT + 63) / 64, 256, 0, stream>>>(awb, BtO2, out);
}

// Round 11
// 185.986 us; speedup vs baseline: 2.3027x; 1.0520x over previous
//
#include <hip/hip_runtime.h>
#include <hip/hip_bf16.h>
#include <math.h>

#define NMAT  50000
#define NOPS  100000
#define NEDGE 512000
#define DOPR  192
#define DEAT  64

typedef __attribute__((ext_vector_type(8))) short bfx8;
typedef __attribute__((ext_vector_type(4))) float fx4;

static __device__ __forceinline__ float lrelu(float x) { return x > 0.f ? x : 0.2f * x; }
static __device__ __forceinline__ float elu(float x)   { return x > 0.f ? x : expm1f(x); }
static __device__ __forceinline__ unsigned short f2bf(float x) {
    unsigned int b = __float_as_uint(x);
    return (unsigned short)((b + 0x7fffu + ((b >> 16) & 1u)) >> 16);   // RNE
}
static __device__ __forceinline__ float bflo(unsigned int u) { return __uint_as_float(u << 16); }
static __device__ __forceinline__ float bfhi(unsigned int u) { return __uint_as_float(u & 0xffff0000u); }
static __device__ __forceinline__ unsigned pk2(float a, float b) {
    return (unsigned)f2bf(a) | ((unsigned)f2bf(b) << 16);
}

// ------- prep (block 0) + weight bf16-transpose conv (blocks 1..96) + cnt zeroing ------
__launch_bounds__(256)
__global__ void k_prepconv(const float* __restrict__ att_self, const float* __restrict__ att_cross,
                           const float* __restrict__ W_mat, const float* __restrict__ W_op,
                           float* __restrict__ asum, float* __restrict__ wv,
                           float* __restrict__ wmc0, float* __restrict__ wmas,
                           float* __restrict__ woc1,
                           unsigned short* __restrict__ BtM, unsigned short* __restrict__ BtO,
                           unsigned short* __restrict__ BtO2, int* __restrict__ cnt)
{
    const int b = blockIdx.x, t = threadIdx.x;
    for (int i = b * 256 + t; i < NMAT; i += 97 * 256) cnt[i] = 0;   // replaces memset
    if (b == 0) {
        __shared__ float as_sh[128];
        if (t < 128) { float v = att_self[t] + att_self[128 + t]; asum[t] = v; as_sh[t] = v; }
        __syncthreads();
        if (t < 128) {
            const float* wr = W_mat + (size_t)t * 128;
            float p0 = 0.f, p1 = 0.f;
            for (int j = 0; j < 128; ++j) { p0 += wr[j] * att_cross[j]; p1 += wr[j] * as_sh[j]; }
            wmc0[t] = p0; wmas[t] = p1;
        }
        const float* wr = W_op + (size_t)t * 128;
        float p = 0.f;
        for (int j = 0; j < 128; ++j) p += wr[j] * att_cross[128 + j];
        if (t < DOPR) woc1[t] = p; else wv[t - DOPR] = p;
    } else {
        int id = (b - 1) * 256 + t;
        if (id < 128 * 128) {
            int c = id >> 7, k = id & 127;
            BtM[c * 128 + k] = f2bf(W_mat[(size_t)k * 128 + c]);
        }
        if (id < 128 * DOPR) {
            int c = id / DOPR, k = id % DOPR;
            BtO[c * DOPR + k] = f2bf(W_op[(size_t)k * 128 + c]);
        }
        if (id < 128 * 64) {       // Wb^T for k_epi: BtO2[c][k2] = W_op[192+k2][c], stride 72
            int c = id >> 6, k = id & 63;
            BtO2[c * 72 + k] = f2bf(W_op[(size_t)(DOPR + k) * 128 + c]);
        }
    }
}

// ---------------- MFMA GEMM body: Cb[M][cstride] = bf16(A[M][K] @ B), fused row-dots ----
// MODE 1: d1 = A.v1 (dm), d2 = lrelu(A.v2) (s_self).  MODE 2: d1 = A.v1 (dop).
// A-tile loads are NONTEMPORAL (stream-once; keep LLC for opb/eab).
template<int K, int MODE>
static __device__ __forceinline__ void gemm_body(
    int bid, unsigned short* As, unsigned short* Bs,
    const float* __restrict__ A, const unsigned short* __restrict__ Bt,
    unsigned short* __restrict__ Cb, int cstride,
    const float* __restrict__ v1, const float* __restrict__ v2,
    float* __restrict__ d1, float* __restrict__ d2, int M)
{
    const int t = threadIdx.x;
    const int w = t >> 6, l = t & 63;
    const int lr = l & 15, lk = l >> 4;
    const int row0 = bid * 128;

    fx4 acc[2][8];
#pragma unroll
    for (int i = 0; i < 2; ++i)
#pragma unroll
        for (int j = 0; j < 8; ++j) acc[i][j] = (fx4){0.f, 0.f, 0.f, 0.f};
    float pd1[4] = {0.f, 0.f, 0.f, 0.f};
    float pd2[4] = {0.f, 0.f, 0.f, 0.f};

    for (int k0 = 0; k0 < K; k0 += 32) {
#pragma unroll
        for (int it = 0; it < 4; ++it) {             // stage A (fp32 -> bf16) + dot partials
            int q  = t + 256 * it;
            int r  = q >> 3;
            int kk = (q & 7) * 4;
            int gr = row0 + r; if (gr >= M) gr = M - 1;
            fx4 v = __builtin_nontemporal_load(
                reinterpret_cast<const fx4*>(A + (size_t)gr * K + k0 + kk));
            ushort4 bb = {f2bf(v[0]), f2bf(v[1]), f2bf(v[2]), f2bf(v[3])};
            *reinterpret_cast<ushort4*>(&As[r * 40 + kk]) = bb;
            pd1[it] += v[0] * v1[k0 + kk] + v[1] * v1[k0 + kk + 1]
                     + v[2] * v1[k0 + kk + 2] + v[3] * v1[k0 + kk + 3];
            if (MODE == 1)
                pd2[it] += v[0] * v2[k0 + kk] + v[1] * v2[k0 + kk + 1]
                         + v[2] * v2[k0 + kk + 2] + v[3] * v2[k0 + kk + 3];
        }
#pragma unroll
        for (int it = 0; it < 2; ++it) {             // stage B chunk (bf16, pre-transposed)
            int q  = t + 256 * it;
            int c  = q >> 2;
            int kg = (q & 3) * 8;
            uint4 vb = *reinterpret_cast<const uint4*>(&Bt[(size_t)c * K + k0 + kg]);
            *reinterpret_cast<uint4*>(&Bs[c * 40 + kg]) = vb;
        }
        __syncthreads();
        bfx8 af0 = *reinterpret_cast<const bfx8*>(&As[(w * 32 + lr) * 40 + lk * 8]);
        bfx8 af1 = *reinterpret_cast<const bfx8*>(&As[(w * 32 + 16 + lr) * 40 + lk * 8]);
#pragma unroll
        for (int ni = 0; ni < 8; ++ni) {
            bfx8 bf = *reinterpret_cast<const bfx8*>(&Bs[(ni * 16 + lr) * 40 + lk * 8]);
            acc[0][ni] = __builtin_amdgcn_mfma_f32_16x16x32_bf16(af0, bf, acc[0][ni], 0, 0, 0);
            acc[1][ni] = __builtin_amdgcn_mfma_f32_16x16x32_bf16(af1, bf, acc[1][ni], 0, 0, 0);
        }
        __syncthreads();
    }

    // C/D layout: col = lane&15, row = (lane>>4)*4 + reg
#pragma unroll
    for (int mi = 0; mi < 2; ++mi)
#pragma unroll
        for (int ni = 0; ni < 8; ++ni)
#pragma unroll
            for (int r2 = 0; r2 < 4; ++r2) {
                int row = row0 + w * 32 + mi * 16 + lk * 4 + r2;
                int col = ni * 16 + lr;
                if (row < M) Cb[(size_t)row * cstride + col] = f2bf(acc[mi][ni][r2]);
            }

    // fused row dots: 8 consecutive threads share one tile row
#pragma unroll
    for (int it = 0; it < 4; ++it) {
        float p1 = pd1[it], p2 = pd2[it];
#pragma unroll
        for (int off = 1; off < 8; off <<= 1) {
            p1 += __shfl_xor(p1, off, 8);
            if (MODE == 1) p2 += __shfl_xor(p2, off, 8);
        }
        int r  = (t + 256 * it) >> 3;
        int gr = row0 + r;
        if ((t & 7) == 0 && gr < M) {
            d1[gr] = p1;
            if (MODE == 1) d2[gr] = lrelu(p2);
        }
    }
}

// ---------------- both GEMMs in one dispatch: blocks [0,391) mat, [391,1173) ops -------
#define GBLK_M ((NMAT + 127) / 128)     // 391
#define GBLK_O ((NOPS + 127) / 128)     // 782
__launch_bounds__(256)
__global__ void k_gemms(const float* __restrict__ materials, const unsigned short* __restrict__ BtM,
                        unsigned short* __restrict__ mb,
                        const float* __restrict__ wmc0, const float* __restrict__ wmas,
                        float* __restrict__ dm, float* __restrict__ s_buf,
                        const float* __restrict__ operations, const unsigned short* __restrict__ BtO,
                        unsigned short* __restrict__ opb,
                        const float* __restrict__ woc1, float* __restrict__ dop)
{
    __shared__ unsigned short As[128 * 40];
    __shared__ unsigned short Bs[128 * 40];
    if (blockIdx.x < GBLK_M)
        gemm_body<128, 1>(blockIdx.x, As, Bs, materials, BtM, mb, 256,
                          wmc0, wmas, dm, s_buf, NMAT);
    else
        gemm_body<192, 2>(blockIdx.x - GBLK_M, As, Bs, operations, BtO, opb, 128,
                          woc1, nullptr, dop, nullptr, NOPS);
}

// ---------------- edge scores + dst histogram + bf16 edge_attr copy ----------------
__launch_bounds__(256)
__global__ void k_edge_score(const float* __restrict__ edge_attr,
                             const int* __restrict__ esrc, const int* __restrict__ edst,
                             const float* __restrict__ dm, const float* __restrict__ dop,
                             const float* __restrict__ wv, float* __restrict__ s,
                             int* __restrict__ cnt, unsigned short* __restrict__ eab)
{
    int t = threadIdx.x;
    int g = t >> 4, q = t & 15;
    float4 wvq = *reinterpret_cast<const float4*>(wv + q * 4);
#pragma unroll
    for (int u = 0; u < 8; ++u) {
        int e = blockIdx.x * 128 + u * 16 + g;
        fx4 av = __builtin_nontemporal_load(
            reinterpret_cast<const fx4*>(edge_attr + (size_t)e * DEAT + q * 4));
        ushort4 bb = {f2bf(av[0]), f2bf(av[1]), f2bf(av[2]), f2bf(av[3])};
        *reinterpret_cast<ushort4*>(&eab[(size_t)e * DEAT + q * 4]) = bb;
        float p = av[0] * wvq.x + av[1] * wvq.y + av[2] * wvq.z + av[3] * wvq.w;
#pragma unroll
        for (int off = 1; off < 16; off <<= 1) p += __shfl_xor(p, off, 16);
        if (q == 0) {
            int d = edst[e];
            s[NMAT + e] = lrelu(p + dm[d] + dop[esrc[e]]);
            atomicAdd(&cnt[d], 1);
        }
    }
}

// ------- fused: softmax partials (blocks 0..1023) + block-local scans (1024..1219) ----
__launch_bounds__(256)
__global__ void k_mid2(const float* __restrict__ s, float* __restrict__ part,
                       const int* __restrict__ cnt, int* __restrict__ loc,
                       int* __restrict__ bsum)
{
    const int t = threadIdx.x;
    if (blockIdx.x < 1024) {
        const int n = NMAT + NEDGE;
        float mx = -INFINITY, sm = 0.f;
        for (int i = blockIdx.x * 256 + t; i < n; i += 1024 * 256) {
            float x = s[i];
            if (x > mx) { sm = sm * expf(mx - x) + 1.f; mx = x; }
            else        { sm += expf(x - mx); }
        }
#pragma unroll
        for (int off = 1; off < 64; off <<= 1) {
            float om = __shfl_xor(mx, off, 64);
            float os = __shfl_xor(sm, off, 64);
            float nm = fmaxf(mx, om);
            sm = sm * expf(mx - nm) + os * expf(om - nm);
            mx = nm;
        }
        __shared__ float wm[4], wsum[4];
        int lane = t & 63, wvi = t >> 6;
        if (lane == 0) { wm[wvi] = mx; wsum[wvi] = sm; }
        __syncthreads();
        if (t == 0) {
            float M = wm[0], S = wsum[0];
            for (int i = 1; i < 4; ++i) {
                float nm = fmaxf(M, wm[i]);
                S = S * expf(M - nm) + wsum[i] * expf(wm[i] - nm);
                M = nm;
            }
            part[2 * blockIdx.x]     = M;
            part[2 * blockIdx.x + 1] = S;
        }
    } else {
        // 256-element block scan of cnt
        const int b = blockIdx.x - 1024;                 // 0..195
        const int idx = b * 256 + t;
        int v = (idx < NMAT) ? cnt[idx] : 0;
        __shared__ int sd[256];
        sd[t] = v;
        __syncthreads();
#pragma unroll
        for (int off = 1; off < 256; off <<= 1) {
            int x = (t >= off) ? sd[t - off] : 0;
            __syncthreads();
            sd[t] += x;
            __syncthreads();
        }
        if (idx < NMAT) loc[idx] = sd[t] - v;            // local exclusive
        if (t == 255) bsum[b] = sd[t];
    }
}

// ---- scan C (blocks 0..195): rowptr/cursor = loc + prefix(bsum); block 196: stats ----
__launch_bounds__(256)
__global__ void k_scanC(const int* __restrict__ loc, const int* __restrict__ bsum,
                        int* __restrict__ rowptr, int* __restrict__ cursor,
                        const float* __restrict__ part, float* __restrict__ stats)
{
    const int b = blockIdx.x, t = threadIdx.x;
    if (b < 196) {
        __shared__ int sd[256];
        sd[t] = (t < b) ? bsum[t] : 0;                   // t<b implies t<196
        __syncthreads();
#pragma unroll
        for (int off = 128; off > 0; off >>= 1) {
            if (t < off) sd[t] += sd[t + off];
            __syncthreads();
        }
        int boffb = sd[0];
        int idx = b * 256 + t;
        if (idx < NMAT) {
            int r = loc[idx] + boffb;
            rowptr[idx] = r;
            cursor[idx] = r;
        }
        if (idx == 0) rowptr[NMAT] = NEDGE;
    } else {
        float mx = -INFINITY, sm = 0.f;
        for (int i = t; i < 1024; i += 256) {
            float M = part[2 * i], S = part[2 * i + 1];
            float nm = fmaxf(mx, M);
            sm = sm * expf(mx - nm) + S * expf(M - nm);
            mx = nm;
        }
#pragma unroll
        for (int off = 1; off < 64; off <<= 1) {
            float om = __shfl_xor(mx, off, 64);
            float os = __shfl_xor(sm, off, 64);
            float nm = fmaxf(mx, om);
            sm = sm * expf(mx - nm) + os * expf(om - nm);
            mx = nm;
        }
        __shared__ float wm[4], wsum[4];
        int lane = t & 63, wv = t >> 6;
        if (lane == 0) { wm[wv] = mx; wsum[wv] = sm; }
        __syncthreads();
        if (t == 0) {
            float M = wm[0], S = wsum[0];
            for (int i = 1; i < 4; ++i) {
                float nm = fmaxf(M, wm[i]);
                S = S * expf(M - nm) + wsum[i] * expf(wm[i] - nm);
                M = nm;
            }
            stats[0] = M;
            stats[1] = 1.f / S;
        }
    }
}

// ---------------- fused CSR fill: one packed uint4 {eid, src, w, 0} per edge ----------
__launch_bounds__(256)
__global__ void k_fill(const int* __restrict__ esrc, const int* __restrict__ edst,
                       const float* __restrict__ s, const float* __restrict__ stats,
                       int* __restrict__ cursor, uint4* __restrict__ csr)
{
    int e = blockIdx.x * 256 + threadIdx.x;
    if (e >= NEDGE) return;
    float wg = expf(s[NMAT + e] - stats[0]) * stats[1];
    int pos = atomicAdd(&cursor[edst[e]], 1);
    csr[pos] = make_uint4((unsigned)e, (unsigned)esrc[e], __float_as_uint(wg), 0u);
}

// ---------------- CSR aggregate (lane-group vectorized gathers) ----------------
// wave per material. 16-lane groups read uint4 slices of DIFFERENT rows:
//   opb row (256B) = 16 lanes x uint4 -> 4 load instrs per 16 edges
//   eab row (128B) =  8 lanes x uint4 -> 2 load instrs per 16 edges
// Column-slice partials reduced via shfl_xor at the end.
// Writes ap (bf16) into out's first row-halves and aw into awb.
__launch_bounds__(256)
__global__ void k_agg(const unsigned short* __restrict__ opb,
                      const unsigned short* __restrict__ eab,
                      const uint4* __restrict__ csr,
                      const int* __restrict__ rowptr,
                      unsigned short* __restrict__ awb, unsigned short* apb)
{
    const int t = threadIdx.x;
    const int w = t >> 6, l = t & 63;
    const int mid = blockIdx.x * 4 + w;
    const int beg = rowptr[mid], end = rowptr[mid + 1];

    float acc[8] = {0.f,0.f,0.f,0.f,0.f,0.f,0.f,0.f};   // opb cols (l&15)*8 ..+8
    float aw[8]  = {0.f,0.f,0.f,0.f,0.f,0.f,0.f,0.f};   // eab cols (l&7)*8 ..+8

    for (int base = beg; base < end; base += 16) {
        int idx = base + (l & 15);
        bool ok = idx < end;
        uint4 mt = csr[ok ? idx : end - 1];
        int   eel = (int)mt.x, ssl = (int)mt.y;
        float wl  = ok ? __uint_as_float(mt.z) : 0.f;
#pragma unroll
        for (int r = 0; r < 4; ++r) {                    // 4 edges per round, all 64 lanes
            int   src = __shfl(ssl, r * 4 + (l >> 4), 64);
            float wr  = __shfl(wl,  r * 4 + (l >> 4), 64);
            uint4 o = *reinterpret_cast<const uint4*>(opb + (size_t)src * 128 + (l & 15) * 8);
            acc[0] += wr * bflo(o.x); acc[1] += wr * bfhi(o.x);
            acc[2] += wr * bflo(o.y); acc[3] += wr * bfhi(o.y);
            acc[4] += wr * bflo(o.z); acc[5] += wr * bfhi(o.z);
            acc[6] += wr * bflo(o.w); acc[7] += wr * bfhi(o.w);
        }
#pragma unroll
        for (int r = 0; r < 2; ++r) {                    // 8 edges per round
            int   e  = __shfl(eel, r * 8 + (l >> 3), 64);
            float wr = __shfl(wl,  r * 8 + (l >> 3), 64);
            uint4 ev = *reinterpret_cast<const uint4*>(eab + (size_t)e * 64 + (l & 7) * 8);
            aw[0] += wr * bflo(ev.x); aw[1] += wr * bfhi(ev.x);
            aw[2] += wr * bflo(ev.y); aw[3] += wr * bfhi(ev.y);
            aw[4] += wr * bflo(ev.z); aw[5] += wr * bfhi(ev.z);
            aw[6] += wr * bflo(ev.w); aw[7] += wr * bfhi(ev.w);
        }
    }
#pragma unroll
    for (int j = 0; j < 8; ++j) {
        acc[j] += __shfl_xor(acc[j], 16, 64);
        acc[j] += __shfl_xor(acc[j], 32, 64);
        aw[j]  += __shfl_xor(aw[j],  8, 64);
        aw[j]  += __shfl_xor(aw[j], 16, 64);
        aw[j]  += __shfl_xor(aw[j], 32, 64);
    }
    if (l < 16) {
        uint4 o = {pk2(acc[0],acc[1]), pk2(acc[2],acc[3]),
                   pk2(acc[4],acc[5]), pk2(acc[6],acc[7])};
        *reinterpret_cast<uint4*>(apb + (size_t)mid * 256 + l * 8) = o;   // out row first half
    }
    if (l < 8) {
        uint4 o = {pk2(aw[0],aw[1]), pk2(aw[2],aw[3]),
                   pk2(aw[4],aw[5]), pk2(aw[6],aw[7])};
        *reinterpret_cast<uint4*>(awb + (size_t)mid * 64 + l * 8) = o;
    }
}

// ------- MFMA epilogue: out = elu(ns*m + ap + awb @ Wb); ap/m read from out halves ----
__launch_bounds__(256)
__global__ void k_epi(const unsigned short* __restrict__ awb,
                      const unsigned short* __restrict__ BtO2,   // [128][72] bf16 Wb^T
                      const float* __restrict__ s, const float* __restrict__ stats,
                      float* out)
{
    __shared__ unsigned short Bs[128 * 72];   // 18 KB
    __shared__ float pL[64 * 132];            // 33.8 KB: ns*m + ap per row
    __shared__ float nsL[64];
    const int t = threadIdx.x;
    const int blockRow0 = blockIdx.x * 64;
    const unsigned short* obase = (const unsigned short*)out;

#pragma unroll
    for (int it = 0; it < 9; ++it) {
        int q = t + 256 * it;
        reinterpret_cast<uint4*>(Bs)[q] = reinterpret_cast<const uint4*>(BtO2)[q];
    }
    if (t < 64) {
        int gr = blockRow0 + t; if (gr >= NMAT) gr = NMAT - 1;
        nsL[t] = expf(s[gr] - stats[0]) * stats[1];
    }
    __syncthreads();
#pragma unroll
    for (int i = 0; i < 4; ++i) {                        // stage combined partial
        int idx = t + 256 * i;                           // 0..1023
        int row = idx >> 4, seg = idx & 15;
        int gr = blockRow0 + row; if (gr >= NMAT) gr = NMAT - 1;
        uint4 ap4 = *reinterpret_cast<const uint4*>(obase + (size_t)gr * 256 + seg * 8);
        uint4 mb4 = *reinterpret_cast<const uint4*>(obase + (size_t)gr * 256 + 128 + seg * 8);
        float ns = nsL[row];
        float* d = &pL[row * 132 + seg * 8];
        d[0] = ns * bflo(mb4.x) + bflo(ap4.x);  d[1] = ns * bfhi(mb4.x) + bfhi(ap4.x);
        d[2] = ns * bflo(mb4.y) + bflo(ap4.y);  d[3] = ns * bfhi(mb4.y) + bfhi(ap4.y);
        d[4] = ns * bflo(mb4.z) + bflo(ap4.z);  d[5] = ns * bfhi(mb4.z) + bfhi(ap4.z);
        d[6] = ns * bflo(mb4.w) + bflo(ap4.w);  d[7] = ns * bfhi(mb4.w) + bfhi(ap4.w);
    }
    __syncthreads();

    const int w = t >> 6, l = t & 63, lr = l & 15, lk = l >> 4;
    const int row0 = blockRow0 + w * 16;

    fx4 acc[8];
#pragma unroll
    for (int ni = 0; ni < 8; ++ni) acc[ni] = (fx4){0.f, 0.f, 0.f, 0.f};

#pragma unroll
    for (int k0 = 0; k0 < 64; k0 += 32) {
        int ar = row0 + lr; if (ar >= NMAT) ar = NMAT - 1;
        bfx8 af = *reinterpret_cast<const bfx8*>(awb + (size_t)ar * 64 + k0 + lk * 8);
#pragma unroll
        for (int ni = 0; ni < 8; ++ni) {
            bfx8 bf = *reinterpret_cast<const bfx8*>(&Bs[(ni * 16 + lr) * 72 + k0 + lk * 8]);
            acc[ni] = __builtin_amdgcn_mfma_f32_16x16x32_bf16(af, bf, acc[ni], 0, 0, 0);
        }
    }

    // C/D: col = ni*16 + (lane&15), row = (lane>>4)*4 + reg
#pragma unroll
    for (int ni = 0; ni < 8; ++ni)
#pragma unroll
        for (int r2 = 0; r2 < 4; ++r2) {
            int lrow = w * 16 + lk * 4 + r2;
            int gr = blockRow0 + lrow;
            if (gr < NMAT) {
                float v = pL[lrow * 132 + ni * 16 + lr] + acc[ni][r2];
                out[(size_t)gr * 128 + ni * 16 + lr] = elu(v);
            }
        }
}

extern "C" void kernel_launch(void* const* d_in, const int* in_sizes, int n_in,
                              void* d_out, int out_size, void* d_ws, size_t ws_size,
                              hipStream_t stream)
{
    const float* materials  = (const float*)d_in[0];
    const float* operations = (const float*)d_in[1];
    const float* edge_attr  = (const float*)d_in[2];
    const int*   esrc       = (const int*)d_in[3];
    const int*   edst       = (const int*)d_in[4];
    const float* W_mat      = (const float*)d_in[5];
    const float* W_op       = (const float*)d_in[6];
    const float* att_self   = (const float*)d_in[7];
    const float* att_cross  = (const float*)d_in[8];
    float* out = (float*)d_out;

    // out rows are 512B: bytes [0,256) hold bf16 ap (written by k_agg),
    // bytes [256,512) hold bf16 m (written by k_gemms); k_epi reads both, writes fp32 out.
    unsigned short* mb  = (unsigned short*)d_out + 128;
    unsigned short* apb = (unsigned short*)d_out;

    char* p = (char*)d_ws;
    auto take = [&](size_t bytes) { char* r = p; p += (bytes + 255) & ~(size_t)255; return r; };

    unsigned short* opb     = (unsigned short*)take((size_t)NOPS * 128 * 2);   // 25.6 MB
    float*          s_buf   = (float*)take((size_t)(NMAT + NEDGE) * 4);        // 2.25 MB
    float*          dm      = (float*)take((size_t)NMAT * 4);
    float*          dop     = (float*)take((size_t)NOPS * 4);
    float*          asum    = (float*)take(128 * 4);
    float*          wv      = (float*)take(64 * 4);
    float*          wmc0    = (float*)take(128 * 4);
    float*          wmas    = (float*)take(128 * 4);
    float*          woc1    = (float*)take(DOPR * 4);
    unsigned short* BtM     = (unsigned short*)take(128 * 128 * 2);
    unsigned short* BtO     = (unsigned short*)take(128 * DOPR * 2);
    unsigned short* BtO2    = (unsigned short*)take(128 * 72 * 2);
    float*          part    = (float*)take(2048 * 4);
    float*          stats   = (float*)take(2 * 4);
    int*            cnt     = (int*)take((size_t)NMAT * 4);
    int*            loc     = (int*)take((size_t)NMAT * 4);
    int*            bsum    = (int*)take(256 * 4);
    int*            rowptr  = (int*)take((size_t)(NMAT + 1) * 4);
    int*            cursor  = (int*)take((size_t)NMAT * 4);
    uint4*          csr     = (uint4*)take((size_t)NEDGE * 16);                // 8.2 MB
    unsigned short* eab     = (unsigned short*)take((size_t)NEDGE * DEAT * 2); // 65.5 MB
    unsigned short* awb     = (unsigned short*)take((size_t)NMAT * 64 * 2);    // 6.4 MB
    (void)ws_size;                                                             // ~110 MB total

    k_prepconv<<<97, 256, 0, stream>>>(att_self, att_cross, W_mat, W_op,
                                       asum, wv, wmc0, wmas, woc1, BtM, BtO, BtO2, cnt);
    k_gemms<<<GBLK_M + GBLK_O, 256, 0, stream>>>(materials, BtM, mb, wmc0, wmas, dm, s_buf,
                                                 operations, BtO, opb, woc1, dop);
    k_edge_score<<<NEDGE / 128, 256, 0, stream>>>(edge_attr, esrc, edst, dm, dop, wv,
                                                  s_buf, cnt, eab);
    k_mid2<<<1024 + 196, 256, 0, stream>>>(s_buf, part, cnt, loc, bsum);
    k_scanC<<<197, 256, 0, stream>>>(loc, bsum, rowptr, cursor, part, stats);
    k_fill<<<NEDGE / 256, 256, 0, stream>>>(esrc, edst, s_buf, stats, cursor, csr);
    k_agg<<<NMAT / 4, 256, 0, stream>>>(opb, eab, csr, rowptr, awb, apb);
    k_epi<<<(NMAT + 63) / 64, 256, 0, stream>>>(awb, BtO2, s_buf, stats, out);
}